// Round 1
// baseline (3088.572 us; speedup 1.0000x reference)
//
#include <hip/hip_runtime.h>
#include <hip/hip_bf16.h>
#include <math.h>

// Problem constants
#define BATCH 2
#define SEQ 1024
#define DMODEL 1024
#define DINNER 2048
#define DSTATE 16
#define DCONV 4
#define DTRANK 64
#define DFF 4096
#define NTOK (BATCH * SEQ)   // 2048 tokens

// ---------------------------------------------------------------------------
// Generic tiled fp32 GEMM: C[M,N] = A[M,K] @ W[N,K]^T  (+ fused epilogues)
// EPI: 0 = none, 1 = softplus(v + bias[n]), 2 = sigmoid(v), 3 = v * extra[m,n]
// WQ : BitNet ternary weight quant on load (ws = max(mean|w|,1e-5))
// ---------------------------------------------------------------------------
template<int EPI, bool WQ>
__global__ __launch_bounds__(256)
void gemm_kernel(const float* __restrict__ A, int lda,
                 const float* __restrict__ W, int ldw,
                 float* __restrict__ C, int ldc,
                 int M, int N, int K,
                 const float* __restrict__ bias,
                 const float* __restrict__ wsum, float wcount_inv,
                 const float* __restrict__ extra)
{
    const int BM = 64, BN = 64, BK = 16;
    __shared__ float As[BK][BM + 1];
    __shared__ float Ws[BK][BN + 1];
    const int tid = threadIdx.x;
    const int tx = tid & 15;        // 0..15 (cols)
    const int ty = tid >> 4;        // 0..15 (rows)
    const int bm = blockIdx.y * BM;
    const int bn = blockIdx.x * BN;

    float wscale = 0.f, inv_ws = 0.f;
    if (WQ) {
        float s = fmaxf(wsum[0] * wcount_inv, 1e-5f);
        wscale = s; inv_ws = 1.f / s;
    }

    float acc[4][4] = {};
    const int lk = tid & 15;        // k within tile for loads
    const int lr = tid >> 4;        // row/col base for loads

    for (int k0 = 0; k0 < K; k0 += BK) {
        // A tile (M always multiple of 64 here, no guard)
        #pragma unroll
        for (int i = 0; i < 4; i++) {
            int m = lr + 16 * i;
            As[lk][m] = A[(size_t)(bm + m) * lda + (k0 + lk)];
        }
        // W tile (guard N)
        #pragma unroll
        for (int i = 0; i < 4; i++) {
            int n = lr + 16 * i;
            float w = 0.f;
            if (bn + n < N) w = W[(size_t)(bn + n) * ldw + (k0 + lk)];
            if (WQ) {
                float q = rintf(w * inv_ws);            // round-half-even == jnp.round
                q = fmaxf(-1.f, fminf(1.f, q));
                w = q * wscale;
            }
            Ws[lk][n] = w;
        }
        __syncthreads();
        #pragma unroll
        for (int k = 0; k < BK; k++) {
            float a[4], b[4];
            #pragma unroll
            for (int i = 0; i < 4; i++) a[i] = As[k][ty * 4 + i];
            #pragma unroll
            for (int j = 0; j < 4; j++) b[j] = Ws[k][tx * 4 + j];
            #pragma unroll
            for (int i = 0; i < 4; i++)
                #pragma unroll
                for (int j = 0; j < 4; j++)
                    acc[i][j] = fmaf(a[i], b[j], acc[i][j]);
        }
        __syncthreads();
    }

    #pragma unroll
    for (int i = 0; i < 4; i++) {
        int m = bm + ty * 4 + i;
        #pragma unroll
        for (int j = 0; j < 4; j++) {
            int n = bn + tx * 4 + j;
            if (n < N) {
                float v = acc[i][j];
                if (EPI == 1) {
                    v += bias[n];
                    v = (v > 20.f) ? v : log1pf(__expf(v));   // softplus
                } else if (EPI == 2) {
                    v = 1.f / (1.f + __expf(-v));             // sigmoid
                } else if (EPI == 3) {
                    v = v * extra[(size_t)m * ldc + n];
                }
                C[(size_t)m * ldc + n] = v;
            }
        }
    }
}

// ---------------------------------------------------------------------------
// Causal depthwise conv1d (k=4) + SiLU. u lives in u_res[:, 0:DINNER].
// ---------------------------------------------------------------------------
__global__ __launch_bounds__(256)
void conv_silu_kernel(const float* __restrict__ u_res,
                      const float* __restrict__ conv_w,
                      const float* __restrict__ conv_b,
                      float* __restrict__ u_out)
{
    int idx = blockIdx.x * blockDim.x + threadIdx.x;
    if (idx >= NTOK * DINNER) return;
    int d = idx & (DINNER - 1);
    int token = idx >> 11;
    int t = token & (SEQ - 1);
    float acc = conv_b[d];
    #pragma unroll
    for (int j = 0; j < DCONV; j++) {
        int tt = t - (DCONV - 1) + j;
        if (tt >= 0) {
            acc = fmaf(conv_w[d * DCONV + j],
                       u_res[(size_t)(token - (DCONV - 1) + j) * (2 * DINNER) + d], acc);
        }
    }
    float sig = 1.f / (1.f + __expf(-acc));
    u_out[(size_t)token * DINNER + d] = acc * sig;
}

// ---------------------------------------------------------------------------
// Selective scan, parallel over (b, d, n). Block = 16 d x 16 n. Grid = 256.
// Fuses deltaA/deltaBu construction, y = (scan + u*D) * silu(res).
// Writes y in-place over u (same thread's element -> safe).
// ---------------------------------------------------------------------------
__global__ __launch_bounds__(256)
void scan_kernel(const float* __restrict__ delta,
                 const float* __restrict__ u,
                 const float* __restrict__ u_res,
                 const float* __restrict__ x_dbl,
                 const float* __restrict__ A_log,
                 const float* __restrict__ Dw,
                 float* __restrict__ y)
{
    const int n  = threadIdx.x & 15;
    const int dl = threadIdx.x >> 4;
    const int b  = blockIdx.x >> 7;
    const int d  = ((blockIdx.x & 127) << 4) + dl;

    const float A_n = -__expf(A_log[d * DSTATE + n]);
    const float Dd  = Dw[d];
    float h = 0.f;
    const int base = b * SEQ;

    for (int t = 0; t < SEQ; t++) {
        const int token = base + t;
        const float dv = delta[(size_t)token * DINNER + d];
        const float uv = u[(size_t)token * DINNER + d];
        const float Bv = x_dbl[(size_t)token * 96 + DTRANK + n];
        const float Cv = x_dbl[(size_t)token * 96 + DTRANK + DSTATE + n];
        const float dA = __expf(dv * A_n);
        h = fmaf(dA, h, dv * Bv * uv);
        float contrib = h * Cv;
        #pragma unroll
        for (int off = 8; off >= 1; off >>= 1)
            contrib += __shfl_xor(contrib, off, 16);
        if (n == 0) {
            float rv = u_res[(size_t)token * (2 * DINNER) + DINNER + d];
            float sig = 1.f / (1.f + __expf(-rv));
            y[(size_t)token * DINNER + d] = (contrib + uv * Dd) * (rv * sig);
        }
    }
}

// ---------------------------------------------------------------------------
// Block reduction helper (blockDim.x == 256)
// ---------------------------------------------------------------------------
__device__ __forceinline__ float block_reduce(float v, float* sh, bool is_max)
{
    int tid = threadIdx.x;
    sh[tid] = v;
    __syncthreads();
    #pragma unroll
    for (int s = 128; s > 0; s >>= 1) {
        if (tid < s) sh[tid] = is_max ? fmaxf(sh[tid], sh[tid + s]) : (sh[tid] + sh[tid + s]);
        __syncthreads();
    }
    float r = sh[0];
    __syncthreads();
    return r;
}

// ---------------------------------------------------------------------------
// rmsnorm(x + add, w) -> h_out; also int8-absmax quantized copy -> q_out
// One block per token row (1024 cols, 256 threads x 4).
// ---------------------------------------------------------------------------
__global__ __launch_bounds__(256)
void rmsnorm_quant_kernel(const float* __restrict__ x,
                          const float* __restrict__ add,
                          const float* __restrict__ w,
                          float* __restrict__ h_out,
                          float* __restrict__ q_out)
{
    __shared__ float sh[256];
    const int row = blockIdx.x;
    const int tid = threadIdx.x;
    float v[4]; float ss = 0.f;
    #pragma unroll
    for (int i = 0; i < 4; i++) {
        int c = tid + 256 * i;
        float s = x[(size_t)row * DMODEL + c] + add[(size_t)row * DMODEL + c];
        v[i] = s; ss = fmaf(s, s, ss);
    }
    float tot = block_reduce(ss, sh, false);
    float scale = rsqrtf(tot * (1.f / DMODEL) + 1e-6f);
    float hv[4]; float amax = 0.f;
    #pragma unroll
    for (int i = 0; i < 4; i++) {
        int c = tid + 256 * i;
        hv[i] = v[i] * scale * w[c];
        amax = fmaxf(amax, fabsf(hv[i]));
    }
    float xm = fmaxf(block_reduce(amax, sh, true), 1e-5f);
    float qs = 127.f / xm, dq = xm / 127.f;
    #pragma unroll
    for (int i = 0; i < 4; i++) {
        int c = tid + 256 * i;
        float q = rintf(hv[i] * qs);
        q = fmaxf(-128.f, fminf(127.f, q));
        h_out[(size_t)row * DMODEL + c] = hv[i];
        q_out[(size_t)row * DMODEL + c] = q * dq;
    }
}

// ---------------------------------------------------------------------------
// Per-row int8-absmax quantization of gu (rows of DFF=4096)
// ---------------------------------------------------------------------------
__global__ __launch_bounds__(256)
void quant_rows_kernel(const float* __restrict__ in, float* __restrict__ out)
{
    __shared__ float sh[256];
    const int row = blockIdx.x;
    const int tid = threadIdx.x;
    float v[16]; float amax = 0.f;
    #pragma unroll
    for (int i = 0; i < 16; i++) {
        int c = tid + 256 * i;
        v[i] = in[(size_t)row * DFF + c];
        amax = fmaxf(amax, fabsf(v[i]));
    }
    float xm = fmaxf(block_reduce(amax, sh, true), 1e-5f);
    float qs = 127.f / xm, dq = xm / 127.f;
    #pragma unroll
    for (int i = 0; i < 16; i++) {
        int c = tid + 256 * i;
        float q = rintf(v[i] * qs);
        q = fmaxf(-128.f, fminf(127.f, q));
        out[(size_t)row * DFF + c] = q * dq;
    }
}

// ---------------------------------------------------------------------------
// Final rmsnorm(h + f, w) -> out
// ---------------------------------------------------------------------------
__global__ __launch_bounds__(256)
void rmsnorm_out_kernel(const float* __restrict__ x,
                        const float* __restrict__ add,
                        const float* __restrict__ w,
                        float* __restrict__ out)
{
    __shared__ float sh[256];
    const int row = blockIdx.x;
    const int tid = threadIdx.x;
    float v[4]; float ss = 0.f;
    #pragma unroll
    for (int i = 0; i < 4; i++) {
        int c = tid + 256 * i;
        float s = x[(size_t)row * DMODEL + c] + add[(size_t)row * DMODEL + c];
        v[i] = s; ss = fmaf(s, s, ss);
    }
    float tot = block_reduce(ss, sh, false);
    float scale = rsqrtf(tot * (1.f / DMODEL) + 1e-6f);
    #pragma unroll
    for (int i = 0; i < 4; i++) {
        int c = tid + 256 * i;
        out[(size_t)row * DMODEL + c] = v[i] * scale * w[c];
    }
}

// ---------------------------------------------------------------------------
// sum(|w|) reduction -> atomicAdd into out (zeroed beforehand)
// ---------------------------------------------------------------------------
__global__ __launch_bounds__(256)
void wabs_kernel(const float* __restrict__ w, int n, float* __restrict__ out)
{
    float s = 0.f;
    for (int i = blockIdx.x * blockDim.x + threadIdx.x; i < n; i += gridDim.x * blockDim.x)
        s += fabsf(w[i]);
    #pragma unroll
    for (int off = 32; off >= 1; off >>= 1) s += __shfl_down(s, off, 64);
    __shared__ float sh[4];
    int lane = threadIdx.x & 63, wv = threadIdx.x >> 6;
    if (lane == 0) sh[wv] = s;
    __syncthreads();
    if (threadIdx.x == 0) atomicAdd(out, sh[0] + sh[1] + sh[2] + sh[3]);
}

// ---------------------------------------------------------------------------
extern "C" void kernel_launch(void* const* d_in, const int* in_sizes, int n_in,
                              void* d_out, int out_size, void* d_ws, size_t ws_size,
                              hipStream_t stream)
{
    const float* x         = (const float*)d_in[0];
    const float* in_proj_w = (const float*)d_in[1];
    const float* conv_w    = (const float*)d_in[2];
    const float* conv_b    = (const float*)d_in[3];
    const float* x_proj_w  = (const float*)d_in[4];
    const float* dt_proj_w = (const float*)d_in[5];
    const float* dt_proj_b = (const float*)d_in[6];
    const float* A_log     = (const float*)d_in[7];
    const float* Dw        = (const float*)d_in[8];
    const float* out_proj_w= (const float*)d_in[9];
    const float* norm1_w   = (const float*)d_in[10];
    const float* gate_w    = (const float*)d_in[11];
    const float* up_w      = (const float*)d_in[12];
    const float* down_w    = (const float*)d_in[13];
    const float* norm2_w   = (const float*)d_in[14];
    float* out = (float*)d_out;

    // workspace layout (floats)
    float* ws = (float*)d_ws;
    const size_t M1 = 1024 * 1024;
    float* u_res  = ws + 0;          // 8M  (2048 x 4096); later reused as gate/gu
    float* u_conv = ws + 8 * M1;     // 4M  (2048 x 2048); later y; later gu_q low half
    float* delta  = ws + 12 * M1;    // 4M  (2048 x 2048); later gu_q high half
    float* x_dbl  = ws + 16 * M1;    // 2048 x 96
    float* out1   = ws + 17 * M1;    // 2M
    float* h1     = ws + 19 * M1;    // 2M
    float* xq1    = ws + 21 * M1;    // 2M
    float* f_buf  = ws + 23 * M1;    // 2M
    float* wsums  = ws + 25 * M1;    // 3 floats
    float* gate   = u_res;           // 8M (reuse)
    float* gu_q   = u_conv;          // 8M (reuse u_conv+delta, both dead by then)

    dim3 blk(256);

    // weight absmean sums (BitLinear)
    hipMemsetAsync(wsums, 0, 4 * sizeof(float), stream);
    wabs_kernel<<<512, blk, 0, stream>>>(gate_w, DFF * DMODEL, wsums + 0);
    wabs_kernel<<<512, blk, 0, stream>>>(up_w,   DFF * DMODEL, wsums + 1);
    wabs_kernel<<<512, blk, 0, stream>>>(down_w, DMODEL * DFF, wsums + 2);

    const float winv = 1.f / (float)(DFF * DMODEL);

    // 1. u_res = x @ in_proj_w^T   [2048, 4096]
    gemm_kernel<0, false><<<dim3(4096 / 64, NTOK / 64), blk, 0, stream>>>(
        x, DMODEL, in_proj_w, DMODEL, u_res, 2 * DINNER,
        NTOK, 2 * DINNER, DMODEL, nullptr, nullptr, 0.f, nullptr);

    // 2. depthwise causal conv + silu
    conv_silu_kernel<<<(NTOK * DINNER) / 256, blk, 0, stream>>>(u_res, conv_w, conv_b, u_conv);

    // 3. x_dbl = u @ x_proj_w^T   [2048, 96]
    gemm_kernel<0, false><<<dim3(2, NTOK / 64), blk, 0, stream>>>(
        u_conv, DINNER, x_proj_w, DINNER, x_dbl, 96,
        NTOK, 96, DINNER, nullptr, nullptr, 0.f, nullptr);

    // 4. delta = softplus(dt @ dt_proj_w^T + b)   [2048, 2048]
    gemm_kernel<1, false><<<dim3(DINNER / 64, NTOK / 64), blk, 0, stream>>>(
        x_dbl, 96, dt_proj_w, DTRANK, delta, DINNER,
        NTOK, DINNER, DTRANK, dt_proj_b, nullptr, 0.f, nullptr);

    // 5. selective scan -> y (in place over u_conv)
    scan_kernel<<<256, blk, 0, stream>>>(delta, u_conv, u_res, x_dbl, A_log, Dw, u_conv);

    // 6. out1 = y @ out_proj_w^T   [2048, 1024]
    gemm_kernel<0, false><<<dim3(DMODEL / 64, NTOK / 64), blk, 0, stream>>>(
        u_conv, DINNER, out_proj_w, DINNER, out1, DMODEL,
        NTOK, DMODEL, DINNER, nullptr, nullptr, 0.f, nullptr);

    // 7. h1 = rmsnorm(x + out1, norm1_w); xq1 = int8-absmax quant(h1)
    rmsnorm_quant_kernel<<<NTOK, blk, 0, stream>>>(x, out1, norm1_w, h1, xq1);

    // 8. gate = sigmoid(xq1 @ wq_gate^T)   [2048, 4096]
    gemm_kernel<2, true><<<dim3(DFF / 64, NTOK / 64), blk, 0, stream>>>(
        xq1, DMODEL, gate_w, DMODEL, gate, DFF,
        NTOK, DFF, DMODEL, nullptr, wsums + 0, winv, nullptr);

    // 9. gu = gate * (xq1 @ wq_up^T)  (in place over gate)
    gemm_kernel<3, true><<<dim3(DFF / 64, NTOK / 64), blk, 0, stream>>>(
        xq1, DMODEL, up_w, DMODEL, gate, DFF,
        NTOK, DFF, DMODEL, nullptr, wsums + 1, winv, gate);

    // 10. gu_q = row-quant(gu)
    quant_rows_kernel<<<NTOK, blk, 0, stream>>>(gate, gu_q);

    // 11. f = gu_q @ wq_down^T   [2048, 1024]
    gemm_kernel<0, true><<<dim3(DMODEL / 64, NTOK / 64), blk, 0, stream>>>(
        gu_q, DFF, down_w, DFF, f_buf, DMODEL,
        NTOK, DMODEL, DFF, nullptr, wsums + 2, winv, nullptr);

    // 12. out = rmsnorm(h1 + f, norm2_w)
    rmsnorm_out_kernel<<<NTOK, blk, 0, stream>>>(h1, f_buf, norm2_w, out);
}

// Round 3
// 696.121 us; speedup vs baseline: 4.4368x; 4.4368x over previous
//
#include <hip/hip_runtime.h>
#include <hip/hip_bf16.h>
#include <math.h>

#define BATCH 2
#define SEQ 1024
#define DMODEL 1024
#define DINNER 2048
#define DSTATE 16
#define DCONV 4
#define DTRANK 64
#define DFF 4096
#define NTOK (BATCH * SEQ)

typedef __attribute__((ext_vector_type(8))) short bf16x8;
typedef __attribute__((ext_vector_type(4))) float f32x4;

#define GLOAD_LDS16(gptr, lptr) \
  __builtin_amdgcn_global_load_lds((const __attribute__((address_space(1))) void*)(gptr), \
                                   (__attribute__((address_space(3))) void*)(lptr), 16, 0, 0)

// ---------------------------------------------------------------------------
// MFMA bf16 GEMM: C[M,N] = A[M,K] @ W[N,K]^T, 128x128 tile, BK=32.
// EPI: 0 none; 1 softplus(v+bias[n]); 2 sigmoid(v*rs[m]*ws); 3 v*rs[m]*ws*extra[m,n];
//      4 v*rs[m]*ws
// WBF16: also write bf16 copy to Cb.
// Requires: M % 128 == 0, K % 32 == 0, lda/ldw % 8 == 0. N guarded.
// ---------------------------------------------------------------------------
template<int EPI, bool WBF16>
__global__ __launch_bounds__(256)
void mfma_gemm(const __hip_bfloat16* __restrict__ A, int lda,
               const __hip_bfloat16* __restrict__ W, int ldw,
               float* __restrict__ C, int ldc,
               __hip_bfloat16* __restrict__ Cb,
               int M, int N, int K,
               const float* __restrict__ bias,
               const float* __restrict__ rowscale,
               const float* __restrict__ wsum, float winv,
               const float* __restrict__ extra)
{
    __shared__ short As[128 * 32];
    __shared__ short Bs[128 * 32];
    const int tid = threadIdx.x;
    const int w = tid >> 6, lane = tid & 63;
    const int bm = blockIdx.y * 128, bn = blockIdx.x * 128;
    const int wm = (w & 1) * 64, wn = (w >> 1) * 64;

    f32x4 zero = {0.f, 0.f, 0.f, 0.f};
    f32x4 acc[4][4];
    #pragma unroll
    for (int i = 0; i < 4; i++)
        #pragma unroll
        for (int j = 0; j < 4; j++) acc[i][j] = zero;

    const int mrow = lane >> 2;     // 0..15
    const int kpart = lane & 3;     // 0..3 -> 8 bf16 each

    for (int k0 = 0; k0 < K; k0 += 32) {
        #pragma unroll
        for (int r = 0; r < 2; r++) {
            int row = r * 64 + w * 16 + mrow;
            const __hip_bfloat16* ga = A + (size_t)(bm + row) * lda + k0 + kpart * 8;
            GLOAD_LDS16(ga, &As[(r * 64 + w * 16) * 32]);
            int nrow = bn + row; if (nrow >= N) nrow = N - 1;
            const __hip_bfloat16* gb = W + (size_t)nrow * ldw + k0 + kpart * 8;
            GLOAD_LDS16(gb, &Bs[(r * 64 + w * 16) * 32]);
        }
        __syncthreads();
        bf16x8 a[4], b[4];
        #pragma unroll
        for (int i = 0; i < 4; i++)
            a[i] = *(const bf16x8*)&As[(wm + 16 * i + (lane & 15)) * 32 + (lane >> 4) * 8];
        #pragma unroll
        for (int j = 0; j < 4; j++)
            b[j] = *(const bf16x8*)&Bs[(wn + 16 * j + (lane & 15)) * 32 + (lane >> 4) * 8];
        #pragma unroll
        for (int i = 0; i < 4; i++)
            #pragma unroll
            for (int j = 0; j < 4; j++)
                acc[i][j] = __builtin_amdgcn_mfma_f32_16x16x32_bf16(a[i], b[j], acc[i][j], 0, 0, 0);
        __syncthreads();
    }

    float wsc = 1.f;
    if (EPI >= 2) wsc = fmaxf(wsum[0] * winv, 1e-5f);

    #pragma unroll
    for (int i = 0; i < 4; i++) {
        #pragma unroll
        for (int r = 0; r < 4; r++) {
            int m = bm + wm + 16 * i + (lane >> 4) * 4 + r;
            float rs = (EPI >= 2) ? rowscale[m] * wsc : 0.f;
            #pragma unroll
            for (int j = 0; j < 4; j++) {
                int n = bn + wn + 16 * j + (lane & 15);
                if (n < N) {
                    float v = acc[i][j][r];
                    if (EPI == 1) {
                        v += bias[n];
                        v = (v > 20.f) ? v : log1pf(__expf(v));
                    } else if (EPI == 2) {
                        v *= rs; v = 1.f / (1.f + __expf(-v));
                    } else if (EPI == 3) {
                        v *= rs; v *= extra[(size_t)m * ldc + n];
                    } else if (EPI == 4) {
                        v *= rs;
                    }
                    C[(size_t)m * ldc + n] = v;
                    if (WBF16) Cb[(size_t)m * ldc + n] = __float2bfloat16(v);
                }
            }
        }
    }
}

// ---------------------------------------------------------------------------
__global__ __launch_bounds__(256)
void f2b_kernel(const float* __restrict__ in, __hip_bfloat16* __restrict__ out, int n)
{
    for (int i = blockIdx.x * blockDim.x + threadIdx.x; i < n; i += gridDim.x * blockDim.x)
        out[i] = __float2bfloat16(in[i]);
}

__global__ __launch_bounds__(256)
void ternarize_kernel(const float* __restrict__ w, __hip_bfloat16* __restrict__ out, int n,
                      const float* __restrict__ wsum, float winv)
{
    float s = fmaxf(wsum[0] * winv, 1e-5f);
    for (int i = blockIdx.x * blockDim.x + threadIdx.x; i < n; i += gridDim.x * blockDim.x) {
        float q = rintf(w[i] / s);
        q = fmaxf(-1.f, fminf(1.f, q));
        out[i] = __float2bfloat16(q);
    }
}

// ---------------------------------------------------------------------------
__global__ __launch_bounds__(256)
void conv_silu_kernel(const float* __restrict__ u_res,
                      const float* __restrict__ conv_w,
                      const float* __restrict__ conv_b,
                      float* __restrict__ u_f, __hip_bfloat16* __restrict__ u_b)
{
    int idx = blockIdx.x * blockDim.x + threadIdx.x;
    if (idx >= NTOK * DINNER) return;
    int d = idx & (DINNER - 1);
    int token = idx >> 11;
    int t = token & (SEQ - 1);
    float acc = conv_b[d];
    #pragma unroll
    for (int j = 0; j < DCONV; j++) {
        int tt = t - (DCONV - 1) + j;
        if (tt >= 0)
            acc = fmaf(conv_w[d * DCONV + j],
                       u_res[(size_t)(token - (DCONV - 1) + j) * (2 * DINNER) + d], acc);
    }
    float sig = 1.f / (1.f + __expf(-acc));
    float v = acc * sig;
    u_f[(size_t)token * DINNER + d] = v;
    u_b[(size_t)token * DINNER + d] = __float2bfloat16(v);
}

// ---------------------------------------------------------------------------
// Chunked selective scan. 16 chunks x 64 steps. Block = 16d x 16n (256 thr).
#define NCH 16
#define CHT 64
__global__ __launch_bounds__(256)
void scan_phaseA(const float* __restrict__ delta, const float* __restrict__ u,
                 const float* __restrict__ x_dbl, const float* __restrict__ A_log,
                 float* __restrict__ hend, float* __restrict__ prodA)
{
    __shared__ float sd[CHT][16], su[CHT][16], sB[CHT][16];
    const int tid = threadIdx.x;
    const int n = tid & 15, dl = tid >> 4;
    const int d0 = blockIdx.x * 16;
    const int c = blockIdx.y, b = blockIdx.z;
    const int t0 = c * CHT;

    #pragma unroll
    for (int i = 0; i < 4; i++) {
        int idx = tid + 256 * i;
        int t = idx >> 4, col = idx & 15;
        int token = (b << 10) + t0 + t;
        sd[t][col] = delta[(size_t)token * DINNER + d0 + col];
        su[t][col] = u[(size_t)token * DINNER + d0 + col];
        sB[t][col] = x_dbl[(size_t)token * 96 + DTRANK + col];
    }
    __syncthreads();

    const float An = -__expf(A_log[(d0 + dl) * DSTATE + n]);
    float h = 0.f, P = 1.f;
    #pragma unroll 4
    for (int t = 0; t < CHT; t++) {
        float dv = sd[t][dl];
        float dA = __expf(dv * An);
        h = fmaf(dA, h, dv * sB[t][n] * su[t][dl]);
        P *= dA;
    }
    size_t chain = ((size_t)(b * DINNER + d0 + dl)) * DSTATE + n;
    hend[(size_t)c * 65536 + chain] = h;
    prodA[(size_t)c * 65536 + chain] = P;
}

__global__ __launch_bounds__(256)
void scan_combine(const float* __restrict__ hend, const float* __restrict__ prodA,
                  float* __restrict__ hin)
{
    int chain = blockIdx.x * 256 + threadIdx.x;
    float h = 0.f;
    #pragma unroll
    for (int c = 0; c < NCH; c++) {
        hin[(size_t)c * 65536 + chain] = h;
        h = hend[(size_t)c * 65536 + chain] + prodA[(size_t)c * 65536 + chain] * h;
    }
}

__global__ __launch_bounds__(256)
void scan_phaseC(const float* __restrict__ delta, const float* __restrict__ u,
                 const float* __restrict__ u_res, const float* __restrict__ x_dbl,
                 const float* __restrict__ A_log, const float* __restrict__ Dw,
                 const float* __restrict__ hin, __hip_bfloat16* __restrict__ y)
{
    __shared__ float sd[CHT][16], su[CHT][16], sB[CHT][16], sC[CHT][16], sres[CHT][16];
    const int tid = threadIdx.x;
    const int n = tid & 15, dl = tid >> 4;
    const int d0 = blockIdx.x * 16;
    const int c = blockIdx.y, b = blockIdx.z;
    const int t0 = c * CHT;

    #pragma unroll
    for (int i = 0; i < 4; i++) {
        int idx = tid + 256 * i;
        int t = idx >> 4, col = idx & 15;
        int token = (b << 10) + t0 + t;
        sd[t][col] = delta[(size_t)token * DINNER + d0 + col];
        su[t][col] = u[(size_t)token * DINNER + d0 + col];
        sB[t][col] = x_dbl[(size_t)token * 96 + DTRANK + col];
        sC[t][col] = x_dbl[(size_t)token * 96 + DTRANK + DSTATE + col];
        sres[t][col] = u_res[(size_t)token * (2 * DINNER) + DINNER + d0 + col];
    }
    __syncthreads();

    const float An = -__expf(A_log[(d0 + dl) * DSTATE + n]);
    const float Dd = Dw[d0 + dl];
    size_t chain = ((size_t)(b * DINNER + d0 + dl)) * DSTATE + n;
    float h = hin[(size_t)c * 65536 + chain];

    for (int t = 0; t < CHT; t++) {
        float dv = sd[t][dl];
        float dA = __expf(dv * An);
        h = fmaf(dA, h, dv * sB[t][n] * su[t][dl]);
        float contrib = h * sC[t][n];
        #pragma unroll
        for (int off = 8; off >= 1; off >>= 1)
            contrib += __shfl_xor(contrib, off, 16);
        if (n == 0) {
            float rv = sres[t][dl];
            float sig = 1.f / (1.f + __expf(-rv));
            int token = (b << 10) + t0 + t;
            y[(size_t)token * DINNER + d0 + dl] =
                __float2bfloat16((contrib + su[t][dl] * Dd) * (rv * sig));
        }
    }
}

// ---------------------------------------------------------------------------
__device__ __forceinline__ float block_reduce(float v, float* sh, bool is_max)
{
    int tid = threadIdx.x;
    sh[tid] = v;
    __syncthreads();
    #pragma unroll
    for (int s = 128; s > 0; s >>= 1) {
        if (tid < s) sh[tid] = is_max ? fmaxf(sh[tid], sh[tid + s]) : (sh[tid] + sh[tid + s]);
        __syncthreads();
    }
    float r = sh[0];
    __syncthreads();
    return r;
}

__global__ __launch_bounds__(256)
void rmsnorm_quant_kernel(const float* __restrict__ x, const float* __restrict__ add,
                          const float* __restrict__ w, float* __restrict__ h_out,
                          __hip_bfloat16* __restrict__ q_out, float* __restrict__ dq_out)
{
    __shared__ float sh[256];
    const int row = blockIdx.x;
    const int tid = threadIdx.x;
    float v[4]; float ss = 0.f;
    #pragma unroll
    for (int i = 0; i < 4; i++) {
        int cidx = tid + 256 * i;
        float s = x[(size_t)row * DMODEL + cidx] + add[(size_t)row * DMODEL + cidx];
        v[i] = s; ss = fmaf(s, s, ss);
    }
    float tot = block_reduce(ss, sh, false);
    float scale = rsqrtf(tot * (1.f / DMODEL) + 1e-6f);
    float hv[4]; float amax = 0.f;
    #pragma unroll
    for (int i = 0; i < 4; i++) {
        int cidx = tid + 256 * i;
        hv[i] = v[i] * scale * w[cidx];
        amax = fmaxf(amax, fabsf(hv[i]));
    }
    float xm = fmaxf(block_reduce(amax, sh, true), 1e-5f);
    float qs = 127.f / xm;
    #pragma unroll
    for (int i = 0; i < 4; i++) {
        int cidx = tid + 256 * i;
        float q = rintf(hv[i] * qs);
        q = fmaxf(-128.f, fminf(127.f, q));
        h_out[(size_t)row * DMODEL + cidx] = hv[i];
        q_out[(size_t)row * DMODEL + cidx] = __float2bfloat16(q);
    }
    if (tid == 0) dq_out[row] = xm / 127.f;
}

__global__ __launch_bounds__(256)
void quant_rows_kernel(const float* __restrict__ in, __hip_bfloat16* __restrict__ out,
                       float* __restrict__ dq_out)
{
    __shared__ float sh[256];
    const int row = blockIdx.x;
    const int tid = threadIdx.x;
    float v[16]; float amax = 0.f;
    #pragma unroll
    for (int i = 0; i < 16; i++) {
        int cidx = tid + 256 * i;
        v[i] = in[(size_t)row * DFF + cidx];
        amax = fmaxf(amax, fabsf(v[i]));
    }
    float xm = fmaxf(block_reduce(amax, sh, true), 1e-5f);
    float qs = 127.f / xm;
    #pragma unroll
    for (int i = 0; i < 16; i++) {
        int cidx = tid + 256 * i;
        float q = rintf(v[i] * qs);
        q = fmaxf(-128.f, fminf(127.f, q));
        out[(size_t)row * DFF + cidx] = __float2bfloat16(q);
    }
    if (tid == 0) dq_out[row] = xm / 127.f;
}

__global__ __launch_bounds__(256)
void rmsnorm_out_kernel(const float* __restrict__ x, const float* __restrict__ add,
                        const float* __restrict__ w, float* __restrict__ out)
{
    __shared__ float sh[256];
    const int row = blockIdx.x;
    const int tid = threadIdx.x;
    float v[4]; float ss = 0.f;
    #pragma unroll
    for (int i = 0; i < 4; i++) {
        int cidx = tid + 256 * i;
        float s = x[(size_t)row * DMODEL + cidx] + add[(size_t)row * DMODEL + cidx];
        v[i] = s; ss = fmaf(s, s, ss);
    }
    float tot = block_reduce(ss, sh, false);
    float scale = rsqrtf(tot * (1.f / DMODEL) + 1e-6f);
    #pragma unroll
    for (int i = 0; i < 4; i++) {
        int cidx = tid + 256 * i;
        out[(size_t)row * DMODEL + cidx] = v[i] * scale * w[cidx];
    }
}

__global__ __launch_bounds__(256)
void wabs_kernel(const float* __restrict__ w, int n, float* __restrict__ out)
{
    float s = 0.f;
    for (int i = blockIdx.x * blockDim.x + threadIdx.x; i < n; i += gridDim.x * blockDim.x)
        s += fabsf(w[i]);
    #pragma unroll
    for (int off = 32; off >= 1; off >>= 1) s += __shfl_down(s, off, 64);
    __shared__ float sh[4];
    int lane = threadIdx.x & 63, wv = threadIdx.x >> 6;
    if (lane == 0) sh[wv] = s;
    __syncthreads();
    if (threadIdx.x == 0) atomicAdd(out, sh[0] + sh[1] + sh[2] + sh[3]);
}

// ---------------------------------------------------------------------------
// Workspace layout (float offsets; M1 = 1M floats). Lifetimes verified:
//  A [0,8M)     u_res (G1..phaseC)            -> gate/gu (G8..quant_rows)
//  B [8M,12M)   u_f (conv..phaseC)            -> f_buf (G11..end)
//  C [12M,14M)  u_b bf16 (conv..G3)           -> y_b bf16 (phaseC..G6)
//  D [14M,18M)  delta (G4..phaseC) -> wq_gate[14M,16M)+wq_up[16M,18M) (tern..G9)
//               -> guq bf16 (quant_rows..G11)
//  E [18M,20M)  w_in_b bf16 (f2b..G1) -> hend[18M,19M)+prodA[19M,20M) (phaseA..combine)
//               -> out1 (G6..rmsq) -> wq_down bf16 (tern_down..G11)
//  F [20M,22M)  hin[20M,21M) (combine..phaseC) + x_b bf16[21M,22M) (f2b..G1)
//               -> h1 (rmsq..end)
//  G [22M,23M)  w_out_b bf16 (f2b..G6)        -> xq_b bf16 (rmsq..G9)
//  J [23M,...)  x_dbl, x_dbl_b, w_x_b, w_dt_b, dq1, dq2, wsums  (~660K)
// Total ~94.7 MB.
// ---------------------------------------------------------------------------
extern "C" void kernel_launch(void* const* d_in, const int* in_sizes, int n_in,
                              void* d_out, int out_size, void* d_ws, size_t ws_size,
                              hipStream_t stream)
{
    const float* x         = (const float*)d_in[0];
    const float* in_proj_w = (const float*)d_in[1];
    const float* conv_w    = (const float*)d_in[2];
    const float* conv_b    = (const float*)d_in[3];
    const float* x_proj_w  = (const float*)d_in[4];
    const float* dt_proj_w = (const float*)d_in[5];
    const float* dt_proj_b = (const float*)d_in[6];
    const float* A_log     = (const float*)d_in[7];
    const float* Dw        = (const float*)d_in[8];
    const float* out_proj_w= (const float*)d_in[9];
    const float* norm1_w   = (const float*)d_in[10];
    const float* gate_w    = (const float*)d_in[11];
    const float* up_w      = (const float*)d_in[12];
    const float* down_w    = (const float*)d_in[13];
    const float* norm2_w   = (const float*)d_in[14];
    float* out = (float*)d_out;

    typedef __hip_bfloat16 bf16;
    float* ws = (float*)d_ws;
    const size_t M1 = 1024 * 1024;

    float* u_res   = ws + 0;                        // A
    float* gate    = ws + 0;
    float* u_f     = ws + 8 * M1;                   // B
    float* f_buf   = ws + 8 * M1;
    bf16*  u_b     = (bf16*)(ws + 12 * M1);         // C
    bf16*  y_b     = (bf16*)(ws + 12 * M1);
    float* delta   = ws + 14 * M1;                  // D
    bf16*  wq_gate = (bf16*)(ws + 14 * M1);
    bf16*  wq_up   = (bf16*)(ws + 16 * M1);
    bf16*  guq     = (bf16*)(ws + 14 * M1);
    bf16*  w_in_b  = (bf16*)(ws + 18 * M1);         // E
    float* hend    = ws + 18 * M1;
    float* prodA   = ws + 19 * M1;
    float* out1    = ws + 18 * M1;
    bf16*  wq_down = (bf16*)(ws + 18 * M1);
    float* hin     = ws + 20 * M1;                  // F
    bf16*  x_b     = (bf16*)(ws + 21 * M1);
    float* h1      = ws + 20 * M1;
    bf16*  w_out_b = (bf16*)(ws + 22 * M1);         // G
    bf16*  xq_b    = (bf16*)(ws + 22 * M1);
    float* x_dbl   = ws + 23 * M1;                  // J (196608 fl)
    bf16*  x_dbl_b = (bf16*)(ws + 23 * M1 + 262144);
    bf16*  w_x_b   = (bf16*)(ws + 23 * M1 + 393216);
    bf16*  w_dt_b  = (bf16*)(ws + 23 * M1 + 524288);
    float* dq1     = ws + 23 * M1 + 655360;
    float* dq2     = ws + 23 * M1 + 659456;
    float* wsums   = ws + 23 * M1 + 663552;

    dim3 blk(256);
    const float winv = 1.f / (float)(DFF * DMODEL);

    hipMemsetAsync(wsums, 0, 16, stream);
    wabs_kernel<<<512, blk, 0, stream>>>(gate_w, DFF * DMODEL, wsums + 0);
    wabs_kernel<<<512, blk, 0, stream>>>(up_w,   DFF * DMODEL, wsums + 1);
    wabs_kernel<<<512, blk, 0, stream>>>(down_w, DMODEL * DFF, wsums + 2);

    // bf16 conversions needed before the mamba GEMMs
    f2b_kernel<<<1024, blk, 0, stream>>>(x, x_b, NTOK * DMODEL);
    f2b_kernel<<<1024, blk, 0, stream>>>(in_proj_w, w_in_b, 2 * DINNER * DMODEL);
    f2b_kernel<<<256, blk, 0, stream>>>(x_proj_w, w_x_b, 96 * DINNER);
    f2b_kernel<<<256, blk, 0, stream>>>(dt_proj_w, w_dt_b, DINNER * DTRANK);
    f2b_kernel<<<1024, blk, 0, stream>>>(out_proj_w, w_out_b, DMODEL * DINNER);

    // 1. u_res = x @ in_proj^T  [2048,4096]
    mfma_gemm<0, false><<<dim3(32, 16), blk, 0, stream>>>(
        x_b, DMODEL, w_in_b, DMODEL, u_res, 2 * DINNER, nullptr,
        NTOK, 2 * DINNER, DMODEL, nullptr, nullptr, nullptr, 0.f, nullptr);

    // 2. conv + silu
    conv_silu_kernel<<<(NTOK * DINNER) / 256, blk, 0, stream>>>(u_res, conv_w, conv_b, u_f, u_b);

    // 3. x_dbl = u @ x_proj^T  [2048,96] (fp32 + bf16)
    mfma_gemm<0, true><<<dim3(1, 16), blk, 0, stream>>>(
        u_b, DINNER, w_x_b, DINNER, x_dbl, 96, x_dbl_b,
        NTOK, 96, DINNER, nullptr, nullptr, nullptr, 0.f, nullptr);

    // 4. delta = softplus(dt @ dt_proj^T + b)  [2048,2048]
    mfma_gemm<1, false><<<dim3(16, 16), blk, 0, stream>>>(
        x_dbl_b, 96, w_dt_b, DTRANK, delta, DINNER, nullptr,
        NTOK, DINNER, DTRANK, dt_proj_b, nullptr, nullptr, 0.f, nullptr);

    // 5. chunked scan -> y_b (overwrites u_b region; u_b dead after G3)
    scan_phaseA<<<dim3(128, NCH, 2), blk, 0, stream>>>(delta, u_f, x_dbl, A_log, hend, prodA);
    scan_combine<<<256, blk, 0, stream>>>(hend, prodA, hin);
    scan_phaseC<<<dim3(128, NCH, 2), blk, 0, stream>>>(delta, u_f, u_res, x_dbl, A_log, Dw, hin, y_b);

    // ternarize gate/up into delta's region (delta dead after phaseC)
    ternarize_kernel<<<1024, blk, 0, stream>>>(gate_w, wq_gate, DFF * DMODEL, wsums + 0, winv);
    ternarize_kernel<<<1024, blk, 0, stream>>>(up_w,   wq_up,   DFF * DMODEL, wsums + 1, winv);

    // 6. out1 = y @ out_proj^T  [2048,1024]  (out1 over hend/prodA; both dead)
    mfma_gemm<0, false><<<dim3(8, 16), blk, 0, stream>>>(
        y_b, DINNER, w_out_b, DINNER, out1, DMODEL, nullptr,
        NTOK, DMODEL, DINNER, nullptr, nullptr, nullptr, 0.f, nullptr);

    // 7. h1 = rmsnorm(x+out1); xq (ints in bf16) + dq1  (h1 over hin; xq over w_out_b)
    rmsnorm_quant_kernel<<<NTOK, blk, 0, stream>>>(x, out1, norm1_w, h1, xq_b, dq1);

    // ternarize down into out1's region (out1 dead after step 7)
    ternarize_kernel<<<1024, blk, 0, stream>>>(down_w, wq_down, DMODEL * DFF, wsums + 2, winv);

    // 8. gate = sigmoid(xq @ wq_gate^T * dq1 * ws)  [2048,4096] (over u_res; dead)
    mfma_gemm<2, false><<<dim3(32, 16), blk, 0, stream>>>(
        xq_b, DMODEL, wq_gate, DMODEL, gate, DFF, nullptr,
        NTOK, DFF, DMODEL, nullptr, dq1, wsums + 0, winv, nullptr);

    // 9. gu = (xq @ wq_up^T * dq1 * ws) * gate  (in place)
    mfma_gemm<3, false><<<dim3(32, 16), blk, 0, stream>>>(
        xq_b, DMODEL, wq_up, DMODEL, gate, DFF, nullptr,
        NTOK, DFF, DMODEL, nullptr, dq1, wsums + 1, winv, gate);

    // 10. guq + dq2  (guq over wq_gate/wq_up; both dead after step 9)
    quant_rows_kernel<<<NTOK, blk, 0, stream>>>(gate, guq, dq2);

    // 11. f = guq @ wq_down^T * dq2 * ws  [2048,1024]  (f over u_f; dead)
    mfma_gemm<4, false><<<dim3(8, 16), blk, 0, stream>>>(
        guq, DFF, wq_down, DFF, f_buf, DMODEL, nullptr,
        NTOK, DMODEL, DFF, nullptr, dq2, wsums + 2, winv, nullptr);

    // 12. out = rmsnorm(h1 + f)
    rmsnorm_out_kernel<<<NTOK, blk, 0, stream>>>(h1, f_buf, norm2_w, out);
}

// Round 4
// 581.820 us; speedup vs baseline: 5.3085x; 1.1965x over previous
//
#include <hip/hip_runtime.h>
#include <hip/hip_bf16.h>
#include <math.h>

#define BATCH 2
#define SEQ 1024
#define DMODEL 1024
#define DINNER 2048
#define DSTATE 16
#define DCONV 4
#define DTRANK 64
#define DFF 4096
#define NTOK (BATCH * SEQ)

typedef __attribute__((ext_vector_type(8))) short bf16x8;
typedef __attribute__((ext_vector_type(4))) float f32x4;

#define GLOAD_LDS16(gptr, lptr) \
  __builtin_amdgcn_global_load_lds((const __attribute__((address_space(1))) void*)(gptr), \
                                   (__attribute__((address_space(3))) void*)(lptr), 16, 0, 0)

// ---------------------------------------------------------------------------
// MFMA bf16 GEMM: C = A[M,K] @ W[N,K]^T, 128x128 tile, BK=32, LDS col-swizzle.
// Split-K via gridDim.z: each z computes K/gridDim.z slice into C + z*part_stride.
// EPI: 0 none; 1 softplus(v+bias[n]); 2 sigmoid(v*rs); 3 v*rs*extra; 4 v*rs
// Swizzle: LDS(row, col) holds global k-group gc = (col - (row>>1)) & 3.
// ---------------------------------------------------------------------------
template<int EPI, bool WBF16>
__global__ __launch_bounds__(256)
void mfma_gemm(const __hip_bfloat16* __restrict__ A, int lda,
               const __hip_bfloat16* __restrict__ W, int ldw,
               float* __restrict__ C, int ldc,
               __hip_bfloat16* __restrict__ Cb,
               int M, int N, int K,
               const float* __restrict__ bias,
               const float* __restrict__ rowscale,
               const float* __restrict__ wsum, float winv,
               const float* __restrict__ extra,
               size_t part_stride)
{
    __shared__ short As[128 * 32];
    __shared__ short Bs[128 * 32];
    const int tid = threadIdx.x;
    const int w = tid >> 6, lane = tid & 63;
    const int bm = blockIdx.y * 128, bn = blockIdx.x * 128;
    const int wm = (w & 1) * 64, wn = (w >> 1) * 64;

    const int Ksp = K / gridDim.z;
    const int kbeg = blockIdx.z * Ksp;
    float* Cw = C + (size_t)blockIdx.z * part_stride;

    f32x4 zero = {0.f, 0.f, 0.f, 0.f};
    f32x4 acc[4][4];
    #pragma unroll
    for (int i = 0; i < 4; i++)
        #pragma unroll
        for (int j = 0; j < 4; j++) acc[i][j] = zero;

    const int mrow = lane >> 2;     // 0..15
    const int kpart = lane & 3;     // 0..3

    for (int k0 = kbeg; k0 < kbeg + Ksp; k0 += 32) {
        #pragma unroll
        for (int r = 0; r < 2; r++) {
            int row = r * 64 + w * 16 + mrow;
            int gc = (kpart - (row >> 1)) & 3;          // swizzled fetch column
            const __hip_bfloat16* ga = A + (size_t)(bm + row) * lda + k0 + gc * 8;
            GLOAD_LDS16(ga, &As[(r * 64 + w * 16) * 32]);
            int nrow = bn + row; if (nrow >= N) nrow = N - 1;
            const __hip_bfloat16* gb = W + (size_t)nrow * ldw + k0 + gc * 8;
            GLOAD_LDS16(gb, &Bs[(r * 64 + w * 16) * 32]);
        }
        __syncthreads();
        bf16x8 a[4], b[4];
        #pragma unroll
        for (int i = 0; i < 4; i++) {
            int row = wm + 16 * i + (lane & 15);
            int col = ((lane >> 4) + (row >> 1)) & 3;
            a[i] = *(const bf16x8*)&As[row * 32 + col * 8];
        }
        #pragma unroll
        for (int j = 0; j < 4; j++) {
            int row = wn + 16 * j + (lane & 15);
            int col = ((lane >> 4) + (row >> 1)) & 3;
            b[j] = *(const bf16x8*)&Bs[row * 32 + col * 8];
        }
        #pragma unroll
        for (int i = 0; i < 4; i++)
            #pragma unroll
            for (int j = 0; j < 4; j++)
                acc[i][j] = __builtin_amdgcn_mfma_f32_16x16x32_bf16(a[i], b[j], acc[i][j], 0, 0, 0);
        __syncthreads();
    }

    float wsc = 1.f;
    if (EPI >= 2) wsc = fmaxf(wsum[0] * winv, 1e-5f);

    #pragma unroll
    for (int i = 0; i < 4; i++) {
        #pragma unroll
        for (int r = 0; r < 4; r++) {
            int m = bm + wm + 16 * i + (lane >> 4) * 4 + r;
            float rs = (EPI >= 2) ? rowscale[m] * wsc : 0.f;
            #pragma unroll
            for (int j = 0; j < 4; j++) {
                int n = bn + wn + 16 * j + (lane & 15);
                if (n < N) {
                    float v = acc[i][j][r];
                    if (EPI == 1) {
                        v += bias[n];
                        v = (v > 20.f) ? v : log1pf(__expf(v));
                    } else if (EPI == 2) {
                        v *= rs; v = 1.f / (1.f + __expf(-v));
                    } else if (EPI == 3) {
                        v *= rs; v *= extra[(size_t)m * ldc + n];
                    } else if (EPI == 4) {
                        v *= rs;
                    }
                    Cw[(size_t)m * ldc + n] = v;
                    if (WBF16) Cb[(size_t)m * ldc + n] = __float2bfloat16(v);
                }
            }
        }
    }
}

// ---------------------------------------------------------------------------
// Fused gate+up: gu = sigmoid(G*rsg) * (U*rsu), G=A@Wg^T, U=A@Wu^T. 128x128.
// ---------------------------------------------------------------------------
__global__ __launch_bounds__(256)
void mfma_gateup(const __hip_bfloat16* __restrict__ A,
                 const __hip_bfloat16* __restrict__ Wg,
                 const __hip_bfloat16* __restrict__ Wu,
                 float* __restrict__ GU,
                 const float* __restrict__ dq,
                 const float* __restrict__ wsum_g, const float* __restrict__ wsum_u,
                 float winv)
{
    __shared__ short As[128 * 32];
    __shared__ short Bg[128 * 32];
    __shared__ short Bu[128 * 32];
    const int tid = threadIdx.x;
    const int w = tid >> 6, lane = tid & 63;
    const int bm = blockIdx.y * 128, bn = blockIdx.x * 128;
    const int wm = (w & 1) * 64, wn = (w >> 1) * 64;

    f32x4 zero = {0.f, 0.f, 0.f, 0.f};
    f32x4 accg[4][4], accu[4][4];
    #pragma unroll
    for (int i = 0; i < 4; i++)
        #pragma unroll
        for (int j = 0; j < 4; j++) { accg[i][j] = zero; accu[i][j] = zero; }

    const int mrow = lane >> 2, kpart = lane & 3;

    for (int k0 = 0; k0 < DMODEL; k0 += 32) {
        #pragma unroll
        for (int r = 0; r < 2; r++) {
            int row = r * 64 + w * 16 + mrow;
            int gc = (kpart - (row >> 1)) & 3;
            GLOAD_LDS16(A  + (size_t)(bm + row) * DMODEL + k0 + gc * 8, &As[(r * 64 + w * 16) * 32]);
            GLOAD_LDS16(Wg + (size_t)(bn + row) * DMODEL + k0 + gc * 8, &Bg[(r * 64 + w * 16) * 32]);
            GLOAD_LDS16(Wu + (size_t)(bn + row) * DMODEL + k0 + gc * 8, &Bu[(r * 64 + w * 16) * 32]);
        }
        __syncthreads();
        bf16x8 a[4], bg[4], bu[4];
        #pragma unroll
        for (int i = 0; i < 4; i++) {
            int row = wm + 16 * i + (lane & 15);
            int col = ((lane >> 4) + (row >> 1)) & 3;
            a[i] = *(const bf16x8*)&As[row * 32 + col * 8];
        }
        #pragma unroll
        for (int j = 0; j < 4; j++) {
            int row = wn + 16 * j + (lane & 15);
            int col = ((lane >> 4) + (row >> 1)) & 3;
            bg[j] = *(const bf16x8*)&Bg[row * 32 + col * 8];
            bu[j] = *(const bf16x8*)&Bu[row * 32 + col * 8];
        }
        #pragma unroll
        for (int i = 0; i < 4; i++)
            #pragma unroll
            for (int j = 0; j < 4; j++) {
                accg[i][j] = __builtin_amdgcn_mfma_f32_16x16x32_bf16(a[i], bg[j], accg[i][j], 0, 0, 0);
                accu[i][j] = __builtin_amdgcn_mfma_f32_16x16x32_bf16(a[i], bu[j], accu[i][j], 0, 0, 0);
            }
        __syncthreads();
    }

    float wsg = fmaxf(wsum_g[0] * winv, 1e-5f);
    float wsu = fmaxf(wsum_u[0] * winv, 1e-5f);

    #pragma unroll
    for (int i = 0; i < 4; i++) {
        #pragma unroll
        for (int r = 0; r < 4; r++) {
            int m = bm + wm + 16 * i + (lane >> 4) * 4 + r;
            float d = dq[m];
            float rsg = d * wsg, rsu = d * wsu;
            #pragma unroll
            for (int j = 0; j < 4; j++) {
                int n = bn + wn + 16 * j + (lane & 15);
                float g = accg[i][j][r] * rsg;
                float u = accu[i][j][r] * rsu;
                GU[(size_t)m * DFF + n] = u / (1.f + __expf(-g));
            }
        }
    }
}

// ---------------------------------------------------------------------------
__global__ __launch_bounds__(256)
void f2b_kernel(const float* __restrict__ in, __hip_bfloat16* __restrict__ out, int n)
{
    for (int i = blockIdx.x * blockDim.x + threadIdx.x; i < n; i += gridDim.x * blockDim.x)
        out[i] = __float2bfloat16(in[i]);
}

__global__ __launch_bounds__(256)
void ternarize_kernel(const float* __restrict__ w, __hip_bfloat16* __restrict__ out, int n,
                      const float* __restrict__ wsum, float winv)
{
    float s = fmaxf(wsum[0] * winv, 1e-5f);
    for (int i = blockIdx.x * blockDim.x + threadIdx.x; i < n; i += gridDim.x * blockDim.x) {
        float q = rintf(w[i] / s);
        q = fmaxf(-1.f, fminf(1.f, q));
        out[i] = __float2bfloat16(q);
    }
}

// reduce 8 x_proj split-K partials -> fp32 + bf16
__global__ __launch_bounds__(256)
void xproj_reduce(const float* __restrict__ parts, float* __restrict__ x_dbl,
                  __hip_bfloat16* __restrict__ x_dbl_b)
{
    int i = blockIdx.x * 256 + threadIdx.x;
    if (i >= NTOK * 96) return;
    float s = 0.f;
    #pragma unroll
    for (int k = 0; k < 8; k++) s += parts[(size_t)k * (NTOK * 96) + i];
    x_dbl[i] = s;
    x_dbl_b[i] = __float2bfloat16(s);
}

// ---------------------------------------------------------------------------
__global__ __launch_bounds__(256)
void conv_silu_kernel(const float* __restrict__ u_res,
                      const float* __restrict__ conv_w,
                      const float* __restrict__ conv_b,
                      float* __restrict__ u_f, __hip_bfloat16* __restrict__ u_b)
{
    int idx = blockIdx.x * blockDim.x + threadIdx.x;
    if (idx >= NTOK * DINNER) return;
    int d = idx & (DINNER - 1);
    int token = idx >> 11;
    int t = token & (SEQ - 1);
    float acc = conv_b[d];
    #pragma unroll
    for (int j = 0; j < DCONV; j++) {
        int tt = t - (DCONV - 1) + j;
        if (tt >= 0)
            acc = fmaf(conv_w[d * DCONV + j],
                       u_res[(size_t)(token - (DCONV - 1) + j) * (2 * DINNER) + d], acc);
    }
    float sig = 1.f / (1.f + __expf(-acc));
    float v = acc * sig;
    u_f[(size_t)token * DINNER + d] = v;
    u_b[(size_t)token * DINNER + d] = __float2bfloat16(v);
}

// ---------------------------------------------------------------------------
#define NCH 16
#define CHT 64
__global__ __launch_bounds__(256)
void scan_phaseA(const float* __restrict__ delta, const float* __restrict__ u,
                 const float* __restrict__ x_dbl, const float* __restrict__ A_log,
                 float* __restrict__ hend, float* __restrict__ prodA)
{
    __shared__ float sd[CHT][16], su[CHT][16], sB[CHT][16];
    const int tid = threadIdx.x;
    const int n = tid & 15, dl = tid >> 4;
    const int d0 = blockIdx.x * 16;
    const int c = blockIdx.y, b = blockIdx.z;
    const int t0 = c * CHT;

    #pragma unroll
    for (int i = 0; i < 4; i++) {
        int idx = tid + 256 * i;
        int t = idx >> 4, col = idx & 15;
        int token = (b << 10) + t0 + t;
        sd[t][col] = delta[(size_t)token * DINNER + d0 + col];
        su[t][col] = u[(size_t)token * DINNER + d0 + col];
        sB[t][col] = x_dbl[(size_t)token * 96 + DTRANK + col];
    }
    __syncthreads();

    const float An = -__expf(A_log[(d0 + dl) * DSTATE + n]);
    float h = 0.f, P = 1.f;
    #pragma unroll 4
    for (int t = 0; t < CHT; t++) {
        float dv = sd[t][dl];
        float dA = __expf(dv * An);
        h = fmaf(dA, h, dv * sB[t][n] * su[t][dl]);
        P *= dA;
    }
    size_t chain = ((size_t)(b * DINNER + d0 + dl)) * DSTATE + n;
    hend[(size_t)c * 65536 + chain] = h;
    prodA[(size_t)c * 65536 + chain] = P;
}

__global__ __launch_bounds__(256)
void scan_combine(const float* __restrict__ hend, const float* __restrict__ prodA,
                  float* __restrict__ hin)
{
    int chain = blockIdx.x * 256 + threadIdx.x;
    float h = 0.f;
    #pragma unroll
    for (int c = 0; c < NCH; c++) {
        hin[(size_t)c * 65536 + chain] = h;
        h = hend[(size_t)c * 65536 + chain] + prodA[(size_t)c * 65536 + chain] * h;
    }
}

__global__ __launch_bounds__(256)
void scan_phaseC(const float* __restrict__ delta, const float* __restrict__ u,
                 const float* __restrict__ u_res, const float* __restrict__ x_dbl,
                 const float* __restrict__ A_log, const float* __restrict__ Dw,
                 const float* __restrict__ hin, __hip_bfloat16* __restrict__ y)
{
    __shared__ float sd[CHT][16], su[CHT][16], sB[CHT][16], sC[CHT][16], sres[CHT][16];
    const int tid = threadIdx.x;
    const int n = tid & 15, dl = tid >> 4;
    const int d0 = blockIdx.x * 16;
    const int c = blockIdx.y, b = blockIdx.z;
    const int t0 = c * CHT;

    #pragma unroll
    for (int i = 0; i < 4; i++) {
        int idx = tid + 256 * i;
        int t = idx >> 4, col = idx & 15;
        int token = (b << 10) + t0 + t;
        sd[t][col] = delta[(size_t)token * DINNER + d0 + col];
        su[t][col] = u[(size_t)token * DINNER + d0 + col];
        sB[t][col] = x_dbl[(size_t)token * 96 + DTRANK + col];
        sC[t][col] = x_dbl[(size_t)token * 96 + DTRANK + DSTATE + col];
        sres[t][col] = u_res[(size_t)token * (2 * DINNER) + DINNER + d0 + col];
    }
    __syncthreads();

    const float An = -__expf(A_log[(d0 + dl) * DSTATE + n]);
    const float Dd = Dw[d0 + dl];
    size_t chain = ((size_t)(b * DINNER + d0 + dl)) * DSTATE + n;
    float h = hin[(size_t)c * 65536 + chain];

    for (int t = 0; t < CHT; t++) {
        float dv = sd[t][dl];
        float dA = __expf(dv * An);
        h = fmaf(dA, h, dv * sB[t][n] * su[t][dl]);
        float contrib = h * sC[t][n];
        #pragma unroll
        for (int off = 8; off >= 1; off >>= 1)
            contrib += __shfl_xor(contrib, off, 16);
        if (n == 0) {
            float rv = sres[t][dl];
            float sig = 1.f / (1.f + __expf(-rv));
            int token = (b << 10) + t0 + t;
            y[(size_t)token * DINNER + d0 + dl] =
                __float2bfloat16((contrib + su[t][dl] * Dd) * (rv * sig));
        }
    }
}

// ---------------------------------------------------------------------------
__device__ __forceinline__ float block_reduce(float v, float* sh, bool is_max)
{
    int tid = threadIdx.x;
    sh[tid] = v;
    __syncthreads();
    #pragma unroll
    for (int s = 128; s > 0; s >>= 1) {
        if (tid < s) sh[tid] = is_max ? fmaxf(sh[tid], sh[tid + s]) : (sh[tid] + sh[tid + s]);
        __syncthreads();
    }
    float r = sh[0];
    __syncthreads();
    return r;
}

// h1 = rmsnorm(x + sum4(parts)); int8 absmax quant -> bf16 ints + dq
__global__ __launch_bounds__(256)
void rmsnorm_quant_kernel(const float* __restrict__ x, const float* __restrict__ parts,
                          size_t pstride, const float* __restrict__ w,
                          float* __restrict__ h_out,
                          __hip_bfloat16* __restrict__ q_out, float* __restrict__ dq_out)
{
    __shared__ float sh[256];
    const int row = blockIdx.x;
    const int tid = threadIdx.x;
    float v[4]; float ss = 0.f;
    #pragma unroll
    for (int i = 0; i < 4; i++) {
        size_t idx = (size_t)row * DMODEL + tid + 256 * i;
        float s = x[idx] + parts[idx] + parts[idx + pstride]
                + parts[idx + 2 * pstride] + parts[idx + 3 * pstride];
        v[i] = s; ss = fmaf(s, s, ss);
    }
    float tot = block_reduce(ss, sh, false);
    float scale = rsqrtf(tot * (1.f / DMODEL) + 1e-6f);
    float hv[4]; float amax = 0.f;
    #pragma unroll
    for (int i = 0; i < 4; i++) {
        int cidx = tid + 256 * i;
        hv[i] = v[i] * scale * w[cidx];
        amax = fmaxf(amax, fabsf(hv[i]));
    }
    float xm = fmaxf(block_reduce(amax, sh, true), 1e-5f);
    float qs = 127.f / xm;
    #pragma unroll
    for (int i = 0; i < 4; i++) {
        int cidx = tid + 256 * i;
        float q = rintf(hv[i] * qs);
        q = fmaxf(-128.f, fminf(127.f, q));
        h_out[(size_t)row * DMODEL + cidx] = hv[i];
        q_out[(size_t)row * DMODEL + cidx] = __float2bfloat16(q);
    }
    if (tid == 0) dq_out[row] = xm / 127.f;
}

__global__ __launch_bounds__(256)
void quant_rows_kernel(const float* __restrict__ in, __hip_bfloat16* __restrict__ out,
                       float* __restrict__ dq_out)
{
    __shared__ float sh[256];
    const int row = blockIdx.x;
    const int tid = threadIdx.x;
    float v[16]; float amax = 0.f;
    #pragma unroll
    for (int i = 0; i < 16; i++) {
        int cidx = tid + 256 * i;
        v[i] = in[(size_t)row * DFF + cidx];
        amax = fmaxf(amax, fabsf(v[i]));
    }
    float xm = fmaxf(block_reduce(amax, sh, true), 1e-5f);
    float qs = 127.f / xm;
    #pragma unroll
    for (int i = 0; i < 16; i++) {
        int cidx = tid + 256 * i;
        float q = rintf(v[i] * qs);
        q = fmaxf(-128.f, fminf(127.f, q));
        out[(size_t)row * DFF + cidx] = __float2bfloat16(q);
    }
    if (tid == 0) dq_out[row] = xm / 127.f;
}

// out = rmsnorm(h1 + sum4(parts)*dq2[row]*ws)
__global__ __launch_bounds__(256)
void rmsnorm_out_kernel(const float* __restrict__ h1, const float* __restrict__ parts,
                        size_t pstride, const float* __restrict__ dq2,
                        const float* __restrict__ wsum, float winv,
                        const float* __restrict__ w, float* __restrict__ out)
{
    __shared__ float sh[256];
    const int row = blockIdx.x;
    const int tid = threadIdx.x;
    float rs = dq2[row] * fmaxf(wsum[0] * winv, 1e-5f);
    float v[4]; float ss = 0.f;
    #pragma unroll
    for (int i = 0; i < 4; i++) {
        size_t idx = (size_t)row * DMODEL + tid + 256 * i;
        float f = (parts[idx] + parts[idx + pstride]
                 + parts[idx + 2 * pstride] + parts[idx + 3 * pstride]) * rs;
        float s = h1[idx] + f;
        v[i] = s; ss = fmaf(s, s, ss);
    }
    float tot = block_reduce(ss, sh, false);
    float scale = rsqrtf(tot * (1.f / DMODEL) + 1e-6f);
    #pragma unroll
    for (int i = 0; i < 4; i++) {
        int cidx = tid + 256 * i;
        out[(size_t)row * DMODEL + cidx] = v[i] * scale * w[cidx];
    }
}

__global__ __launch_bounds__(256)
void wabs_kernel(const float* __restrict__ w, int n, float* __restrict__ out)
{
    float s = 0.f;
    for (int i = blockIdx.x * blockDim.x + threadIdx.x; i < n; i += gridDim.x * blockDim.x)
        s += fabsf(w[i]);
    #pragma unroll
    for (int off = 32; off >= 1; off >>= 1) s += __shfl_down(s, off, 64);
    __shared__ float sh[4];
    int lane = threadIdx.x & 63, wv = threadIdx.x >> 6;
    if (lane == 0) sh[wv] = s;
    __syncthreads();
    if (threadIdx.x == 0) atomicAdd(out, sh[0] + sh[1] + sh[2] + sh[3]);
}

// ---------------------------------------------------------------------------
// Workspace (float offsets; M1 = 1M floats):
//  A [0,8M)    u_res (G1..phaseC) -> out_parts 4x2M (G6..rmsq) -> gu (G8..qrows)
//              -> down_parts 4x2M (G11..rmsout)
//  B [8M,12M)  u_f (conv..phaseC)
//  C [12M,14M) u_b bf16 (conv..G3) -> y_b bf16 (phaseC..G6)
//  D [14M,18M) delta (G4..phaseC) -> wq_gate+wq_up (tern..G8) -> guq (qrows..G11)
//  E [18M,20M) w_in_b (f2b..G1) -> hend+prodA (phaseA..combine) -> wq_down (..G11)
//  F [20M,22M) hin [20M,21M) + x_b [21M,22M) -> h1 (rmsq..end)
//  G [22M,23M) w_out_b bf16 (..G6) -> xq_b bf16 (rmsq..G8)
//  J [23M,24M) x_dbl, x_dbl_b, w_x_b, w_dt_b, dq1, dq2, wsums
//  X [24M,25.5M) x_proj split-K partials (G3..reduce)
// ---------------------------------------------------------------------------
extern "C" void kernel_launch(void* const* d_in, const int* in_sizes, int n_in,
                              void* d_out, int out_size, void* d_ws, size_t ws_size,
                              hipStream_t stream)
{
    const float* x         = (const float*)d_in[0];
    const float* in_proj_w = (const float*)d_in[1];
    const float* conv_w    = (const float*)d_in[2];
    const float* conv_b    = (const float*)d_in[3];
    const float* x_proj_w  = (const float*)d_in[4];
    const float* dt_proj_w = (const float*)d_in[5];
    const float* dt_proj_b = (const float*)d_in[6];
    const float* A_log     = (const float*)d_in[7];
    const float* Dw        = (const float*)d_in[8];
    const float* out_proj_w= (const float*)d_in[9];
    const float* norm1_w   = (const float*)d_in[10];
    const float* gate_w    = (const float*)d_in[11];
    const float* up_w      = (const float*)d_in[12];
    const float* down_w    = (const float*)d_in[13];
    const float* norm2_w   = (const float*)d_in[14];
    float* out = (float*)d_out;

    typedef __hip_bfloat16 bf16;
    float* ws = (float*)d_ws;
    const size_t M1 = 1024 * 1024;

    float* u_res    = ws + 0;                        // A
    float* op_parts = ws + 0;                        // 4 x 2M
    float* gu       = ws + 0;                        // 8M
    float* dn_parts = ws + 0;                        // 4 x 2M
    float* u_f      = ws + 8 * M1;                   // B
    bf16*  u_b      = (bf16*)(ws + 12 * M1);         // C
    bf16*  y_b      = (bf16*)(ws + 12 * M1);
    float* delta    = ws + 14 * M1;                  // D
    bf16*  wq_gate  = (bf16*)(ws + 14 * M1);
    bf16*  wq_up    = (bf16*)(ws + 16 * M1);
    bf16*  guq      = (bf16*)(ws + 14 * M1);
    bf16*  w_in_b   = (bf16*)(ws + 18 * M1);         // E
    float* hend     = ws + 18 * M1;
    float* prodA    = ws + 19 * M1;
    bf16*  wq_down  = (bf16*)(ws + 18 * M1);
    float* hin      = ws + 20 * M1;                  // F
    bf16*  x_b      = (bf16*)(ws + 21 * M1);
    float* h1       = ws + 20 * M1;
    bf16*  w_out_b  = (bf16*)(ws + 22 * M1);         // G
    bf16*  xq_b     = (bf16*)(ws + 22 * M1);
    float* x_dbl    = ws + 23 * M1;                  // J
    bf16*  x_dbl_b  = (bf16*)(ws + 23 * M1 + 262144);
    bf16*  w_x_b    = (bf16*)(ws + 23 * M1 + 393216);
    bf16*  w_dt_b   = (bf16*)(ws + 23 * M1 + 524288);
    float* dq1      = ws + 23 * M1 + 655360;
    float* dq2      = ws + 23 * M1 + 659456;
    float* wsums    = ws + 23 * M1 + 663552;
    float* x_parts  = ws + 24 * M1;                  // X (8 x 196608)

    dim3 blk(256);
    const float winv = 1.f / (float)(DFF * DMODEL);

    hipMemsetAsync(wsums, 0, 16, stream);
    wabs_kernel<<<512, blk, 0, stream>>>(gate_w, DFF * DMODEL, wsums + 0);
    wabs_kernel<<<512, blk, 0, stream>>>(up_w,   DFF * DMODEL, wsums + 1);
    wabs_kernel<<<512, blk, 0, stream>>>(down_w, DMODEL * DFF, wsums + 2);

    f2b_kernel<<<1024, blk, 0, stream>>>(x, x_b, NTOK * DMODEL);
    f2b_kernel<<<1024, blk, 0, stream>>>(in_proj_w, w_in_b, 2 * DINNER * DMODEL);
    f2b_kernel<<<256, blk, 0, stream>>>(x_proj_w, w_x_b, 96 * DINNER);
    f2b_kernel<<<256, blk, 0, stream>>>(dt_proj_w, w_dt_b, DINNER * DTRANK);
    f2b_kernel<<<1024, blk, 0, stream>>>(out_proj_w, w_out_b, DMODEL * DINNER);

    // 1. u_res = x @ in_proj^T  [2048,4096]
    mfma_gemm<0, false><<<dim3(32, 16), blk, 0, stream>>>(
        x_b, DMODEL, w_in_b, DMODEL, u_res, 2 * DINNER, nullptr,
        NTOK, 2 * DINNER, DMODEL, nullptr, nullptr, nullptr, 0.f, nullptr, 0);

    // 2. conv + silu
    conv_silu_kernel<<<(NTOK * DINNER) / 256, blk, 0, stream>>>(u_res, conv_w, conv_b, u_f, u_b);

    // 3. x_dbl = u @ x_proj^T  [2048,96], split-K=8 -> reduce
    mfma_gemm<0, false><<<dim3(1, 16, 8), blk, 0, stream>>>(
        u_b, DINNER, w_x_b, DINNER, x_parts, 96, nullptr,
        NTOK, 96, DINNER, nullptr, nullptr, nullptr, 0.f, nullptr, NTOK * 96);
    xproj_reduce<<<(NTOK * 96 + 255) / 256, blk, 0, stream>>>(x_parts, x_dbl, x_dbl_b);

    // 4. delta = softplus(dt @ dt_proj^T + b)  [2048,2048]
    mfma_gemm<1, false><<<dim3(16, 16), blk, 0, stream>>>(
        x_dbl_b, 96, w_dt_b, DTRANK, delta, DINNER, nullptr,
        NTOK, DINNER, DTRANK, dt_proj_b, nullptr, nullptr, 0.f, nullptr, 0);

    // 5. chunked scan -> y_b
    scan_phaseA<<<dim3(128, NCH, 2), blk, 0, stream>>>(delta, u_f, x_dbl, A_log, hend, prodA);
    scan_combine<<<256, blk, 0, stream>>>(hend, prodA, hin);
    // ternarize down into E (hend/prodA dead after combine)
    ternarize_kernel<<<1024, blk, 0, stream>>>(down_w, wq_down, DMODEL * DFF, wsums + 2, winv);
    scan_phaseC<<<dim3(128, NCH, 2), blk, 0, stream>>>(delta, u_f, u_res, x_dbl, A_log, Dw, hin, y_b);

    // ternarize gate/up into D (delta dead after phaseC)
    ternarize_kernel<<<1024, blk, 0, stream>>>(gate_w, wq_gate, DFF * DMODEL, wsums + 0, winv);
    ternarize_kernel<<<1024, blk, 0, stream>>>(up_w,   wq_up,   DFF * DMODEL, wsums + 1, winv);

    // 6. out_proj split-K=4 -> op_parts (region A; u_res dead after phaseC)
    mfma_gemm<0, false><<<dim3(8, 16, 4), blk, 0, stream>>>(
        y_b, DINNER, w_out_b, DINNER, op_parts, DMODEL, nullptr,
        NTOK, DMODEL, DINNER, nullptr, nullptr, nullptr, 0.f, nullptr, 2 * M1);

    // 7. h1 = rmsnorm(x + sum(op_parts)); xq + dq1
    rmsnorm_quant_kernel<<<NTOK, blk, 0, stream>>>(x, op_parts, 2 * M1, norm1_w, h1, xq_b, dq1);

    // 8. gu = sigmoid(gate)*up fused  [2048,4096] (region A; op_parts dead)
    mfma_gateup<<<dim3(32, 16), blk, 0, stream>>>(
        xq_b, wq_gate, wq_up, gu, dq1, wsums + 0, wsums + 1, winv);

    // 10. guq + dq2 (region D; wq_gate/up dead)
    quant_rows_kernel<<<NTOK, blk, 0, stream>>>(gu, guq, dq2);

    // 11. down split-K=4 -> dn_parts (region A; gu dead after qrows)
    mfma_gemm<0, false><<<dim3(8, 16, 4), blk, 0, stream>>>(
        guq, DFF, wq_down, DFF, dn_parts, DMODEL, nullptr,
        NTOK, DMODEL, DFF, nullptr, nullptr, nullptr, 0.f, nullptr, 2 * M1);

    // 12. out = rmsnorm(h1 + sum(dn_parts)*dq2*ws)
    rmsnorm_out_kernel<<<NTOK, blk, 0, stream>>>(h1, dn_parts, 2 * M1, dq2,
                                                 wsums + 2, winv, norm2_w, out);
}

// Round 5
// 538.448 us; speedup vs baseline: 5.7361x; 1.0805x over previous
//
#include <hip/hip_runtime.h>
#include <hip/hip_bf16.h>
#include <math.h>

#define BATCH 2
#define SEQ 1024
#define DMODEL 1024
#define DINNER 2048
#define DSTATE 16
#define DCONV 4
#define DTRANK 64
#define DFF 4096
#define NTOK (BATCH * SEQ)

typedef __attribute__((ext_vector_type(8))) short bf16x8;
typedef __attribute__((ext_vector_type(4))) float f32x4;

#define GLOAD_LDS16(gptr, lptr) \
  __builtin_amdgcn_global_load_lds((const __attribute__((address_space(1))) void*)(gptr), \
                                   (__attribute__((address_space(3))) void*)(lptr), 16, 0, 0)

// ---------------------------------------------------------------------------
// MFMA bf16 GEMM: C = A[M,K] @ W[N,K]^T, 128x128 tile, BK=32, LDS col-swizzle.
// Split-K via gridDim.z. EPI: 0 none; 1 softplus(v+bias[n]).
// ---------------------------------------------------------------------------
template<int EPI, bool WBF16>
__global__ __launch_bounds__(256)
void mfma_gemm(const __hip_bfloat16* __restrict__ A, int lda,
               const __hip_bfloat16* __restrict__ W, int ldw,
               float* __restrict__ C, int ldc,
               __hip_bfloat16* __restrict__ Cb,
               int M, int N, int K,
               const float* __restrict__ bias,
               size_t part_stride)
{
    __shared__ short As[128 * 32];
    __shared__ short Bs[128 * 32];
    const int tid = threadIdx.x;
    const int w = tid >> 6, lane = tid & 63;
    const int bm = blockIdx.y * 128, bn = blockIdx.x * 128;
    const int wm = (w & 1) * 64, wn = (w >> 1) * 64;

    const int Ksp = K / gridDim.z;
    const int kbeg = blockIdx.z * Ksp;
    float* Cw = C + (size_t)blockIdx.z * part_stride;

    f32x4 zero = {0.f, 0.f, 0.f, 0.f};
    f32x4 acc[4][4];
    #pragma unroll
    for (int i = 0; i < 4; i++)
        #pragma unroll
        for (int j = 0; j < 4; j++) acc[i][j] = zero;

    const int mrow = lane >> 2;
    const int kpart = lane & 3;

    for (int k0 = kbeg; k0 < kbeg + Ksp; k0 += 32) {
        #pragma unroll
        for (int r = 0; r < 2; r++) {
            int row = r * 64 + w * 16 + mrow;
            int gc = (kpart - (row >> 1)) & 3;
            const __hip_bfloat16* ga = A + (size_t)(bm + row) * lda + k0 + gc * 8;
            GLOAD_LDS16(ga, &As[(r * 64 + w * 16) * 32]);
            int nrow = bn + row; if (nrow >= N) nrow = N - 1;
            const __hip_bfloat16* gb = W + (size_t)nrow * ldw + k0 + gc * 8;
            GLOAD_LDS16(gb, &Bs[(r * 64 + w * 16) * 32]);
        }
        __syncthreads();
        bf16x8 a[4], b[4];
        #pragma unroll
        for (int i = 0; i < 4; i++) {
            int row = wm + 16 * i + (lane & 15);
            int col = ((lane >> 4) + (row >> 1)) & 3;
            a[i] = *(const bf16x8*)&As[row * 32 + col * 8];
        }
        #pragma unroll
        for (int j = 0; j < 4; j++) {
            int row = wn + 16 * j + (lane & 15);
            int col = ((lane >> 4) + (row >> 1)) & 3;
            b[j] = *(const bf16x8*)&Bs[row * 32 + col * 8];
        }
        #pragma unroll
        for (int i = 0; i < 4; i++)
            #pragma unroll
            for (int j = 0; j < 4; j++)
                acc[i][j] = __builtin_amdgcn_mfma_f32_16x16x32_bf16(a[i], b[j], acc[i][j], 0, 0, 0);
        __syncthreads();
    }

    #pragma unroll
    for (int i = 0; i < 4; i++) {
        #pragma unroll
        for (int r = 0; r < 4; r++) {
            int m = bm + wm + 16 * i + (lane >> 4) * 4 + r;
            #pragma unroll
            for (int j = 0; j < 4; j++) {
                int n = bn + wn + 16 * j + (lane & 15);
                if (n < N) {
                    float v = acc[i][j][r];
                    if (EPI == 1) {
                        v += bias[n];
                        v = (v > 20.f) ? v : log1pf(__expf(v));
                    }
                    Cw[(size_t)m * ldc + n] = v;
                    if (WBF16) Cb[(size_t)m * ldc + n] = __float2bfloat16(v);
                }
            }
        }
    }
}

// ---------------------------------------------------------------------------
// Fused gate+up: gu = sigmoid(G*rsg) * (U*rsu). 128x128 tile.
// ---------------------------------------------------------------------------
__global__ __launch_bounds__(256)
void mfma_gateup(const __hip_bfloat16* __restrict__ A,
                 const __hip_bfloat16* __restrict__ Wg,
                 const __hip_bfloat16* __restrict__ Wu,
                 float* __restrict__ GU,
                 const float* __restrict__ dq,
                 const float* __restrict__ wsum_g, const float* __restrict__ wsum_u,
                 float winv)
{
    __shared__ short As[128 * 32];
    __shared__ short Bg[128 * 32];
    __shared__ short Bu[128 * 32];
    const int tid = threadIdx.x;
    const int w = tid >> 6, lane = tid & 63;
    const int bm = blockIdx.y * 128, bn = blockIdx.x * 128;
    const int wm = (w & 1) * 64, wn = (w >> 1) * 64;

    f32x4 zero = {0.f, 0.f, 0.f, 0.f};
    f32x4 accg[4][4], accu[4][4];
    #pragma unroll
    for (int i = 0; i < 4; i++)
        #pragma unroll
        for (int j = 0; j < 4; j++) { accg[i][j] = zero; accu[i][j] = zero; }

    const int mrow = lane >> 2, kpart = lane & 3;

    for (int k0 = 0; k0 < DMODEL; k0 += 32) {
        #pragma unroll
        for (int r = 0; r < 2; r++) {
            int row = r * 64 + w * 16 + mrow;
            int gc = (kpart - (row >> 1)) & 3;
            GLOAD_LDS16(A  + (size_t)(bm + row) * DMODEL + k0 + gc * 8, &As[(r * 64 + w * 16) * 32]);
            GLOAD_LDS16(Wg + (size_t)(bn + row) * DMODEL + k0 + gc * 8, &Bg[(r * 64 + w * 16) * 32]);
            GLOAD_LDS16(Wu + (size_t)(bn + row) * DMODEL + k0 + gc * 8, &Bu[(r * 64 + w * 16) * 32]);
        }
        __syncthreads();
        bf16x8 a[4], bg[4], bu[4];
        #pragma unroll
        for (int i = 0; i < 4; i++) {
            int row = wm + 16 * i + (lane & 15);
            int col = ((lane >> 4) + (row >> 1)) & 3;
            a[i] = *(const bf16x8*)&As[row * 32 + col * 8];
        }
        #pragma unroll
        for (int j = 0; j < 4; j++) {
            int row = wn + 16 * j + (lane & 15);
            int col = ((lane >> 4) + (row >> 1)) & 3;
            bg[j] = *(const bf16x8*)&Bg[row * 32 + col * 8];
            bu[j] = *(const bf16x8*)&Bu[row * 32 + col * 8];
        }
        #pragma unroll
        for (int i = 0; i < 4; i++)
            #pragma unroll
            for (int j = 0; j < 4; j++) {
                accg[i][j] = __builtin_amdgcn_mfma_f32_16x16x32_bf16(a[i], bg[j], accg[i][j], 0, 0, 0);
                accu[i][j] = __builtin_amdgcn_mfma_f32_16x16x32_bf16(a[i], bu[j], accu[i][j], 0, 0, 0);
            }
        __syncthreads();
    }

    float wsg = fmaxf(wsum_g[0] * winv, 1e-5f);
    float wsu = fmaxf(wsum_u[0] * winv, 1e-5f);

    #pragma unroll
    for (int i = 0; i < 4; i++) {
        #pragma unroll
        for (int r = 0; r < 4; r++) {
            int m = bm + wm + 16 * i + (lane >> 4) * 4 + r;
            float d = dq[m];
            float rsg = d * wsg, rsu = d * wsu;
            #pragma unroll
            for (int j = 0; j < 4; j++) {
                int n = bn + wn + 16 * j + (lane & 15);
                float g = accg[i][j][r] * rsg;
                float u = accu[i][j][r] * rsu;
                GU[(size_t)m * DFF + n] = u / (1.f + __expf(-g));
            }
        }
    }
}

// ---------------------------------------------------------------------------
__global__ __launch_bounds__(256)
void f2b_kernel(const float* __restrict__ in, __hip_bfloat16* __restrict__ out, int n)
{
    for (int i = blockIdx.x * blockDim.x + threadIdx.x; i < n; i += gridDim.x * blockDim.x)
        out[i] = __float2bfloat16(in[i]);
}

__global__ __launch_bounds__(256)
void ternarize_kernel(const float* __restrict__ w, __hip_bfloat16* __restrict__ out, int n,
                      const float* __restrict__ wsum, float winv)
{
    float s = fmaxf(wsum[0] * winv, 1e-5f);
    for (int i = blockIdx.x * blockDim.x + threadIdx.x; i < n; i += gridDim.x * blockDim.x) {
        float q = rintf(w[i] / s);
        q = fmaxf(-1.f, fminf(1.f, q));
        out[i] = __float2bfloat16(q);
    }
}

__global__ __launch_bounds__(256)
void xproj_reduce(const float* __restrict__ parts, float* __restrict__ x_dbl,
                  __hip_bfloat16* __restrict__ x_dbl_b)
{
    int i = blockIdx.x * 256 + threadIdx.x;
    if (i >= NTOK * 96) return;
    float s = 0.f;
    #pragma unroll
    for (int k = 0; k < 8; k++) s += parts[(size_t)k * (NTOK * 96) + i];
    x_dbl[i] = s;
    x_dbl_b[i] = __float2bfloat16(s);
}

// ---------------------------------------------------------------------------
__global__ __launch_bounds__(256)
void conv_silu_kernel(const float* __restrict__ u_res,
                      const float* __restrict__ conv_w,
                      const float* __restrict__ conv_b,
                      float* __restrict__ u_f, __hip_bfloat16* __restrict__ u_b)
{
    int idx = blockIdx.x * blockDim.x + threadIdx.x;
    if (idx >= NTOK * DINNER) return;
    int d = idx & (DINNER - 1);
    int token = idx >> 11;
    int t = token & (SEQ - 1);
    float acc = conv_b[d];
    #pragma unroll
    for (int j = 0; j < DCONV; j++) {
        int tt = t - (DCONV - 1) + j;
        if (tt >= 0)
            acc = fmaf(conv_w[d * DCONV + j],
                       u_res[(size_t)(token - (DCONV - 1) + j) * (2 * DINNER) + d], acc);
    }
    float sig = 1.f / (1.f + __expf(-acc));
    float v = acc * sig;
    u_f[(size_t)token * DINNER + d] = v;
    u_b[(size_t)token * DINNER + d] = __float2bfloat16(v);
}

// ---------------------------------------------------------------------------
// Chunked scan, thread-per-d: 16 n-states in registers, no shuffles.
// NCH=64 chunks x CHT=16 steps. Block 256 = 4 waves; wave w -> chunk cg*4+w,
// all waves share d-group blockIdx.x (64 d). Grid (32, 16, 2).
// ---------------------------------------------------------------------------
#define NCH 64
#define CHT 16
__global__ __launch_bounds__(256)
void scan_phaseA(const float* __restrict__ delta, const float* __restrict__ u,
                 const float* __restrict__ x_dbl, const float* __restrict__ A_log,
                 float2* __restrict__ hA)
{
    __shared__ float sB[64][16];
    const int tid = threadIdx.x;
    const int b = blockIdx.z, cg = blockIdx.y;
    const int lane = tid & 63, w = tid >> 6;
    const int d = blockIdx.x * 64 + lane;
    const int c = cg * 4 + w;
    const int tok0 = b * SEQ + cg * 64;

    #pragma unroll
    for (int i = 0; i < 4; i++) {
        int e = tid + 256 * i;
        int tt = e >> 4, n = e & 15;
        sB[tt][n] = x_dbl[(size_t)(tok0 + tt) * 96 + DTRANK + n];
    }
    __syncthreads();

    float An[16];
    #pragma unroll
    for (int n = 0; n < 16; n++) An[n] = -__expf(A_log[d * 16 + n]);

    float h[16];
    #pragma unroll
    for (int n = 0; n < 16; n++) h[n] = 0.f;
    float sdv = 0.f;
    const int tw0 = w * CHT;

    for (int t = 0; t < CHT; t++) {
        int tok = tok0 + tw0 + t;
        float dv = delta[(size_t)tok * DINNER + d];
        float uv = u[(size_t)tok * DINNER + d];
        float duv = dv * uv;
        sdv += dv;
        #pragma unroll
        for (int n = 0; n < 16; n++) {
            float dA = __expf(dv * An[n]);
            h[n] = fmaf(dA, h[n], sB[tw0 + t][n] * duv);
        }
    }
    size_t base = (size_t)c * 65536 + ((size_t)(b * DINNER + d)) * 16;
    #pragma unroll
    for (int n = 0; n < 16; n++) {
        float2 v; v.x = h[n]; v.y = __expf(An[n] * sdv);   // prod(dA) = exp(An*sum dv)
        hA[base + n] = v;
    }
}

__global__ __launch_bounds__(256)
void scan_combine(const float2* __restrict__ hA, float* __restrict__ hin)
{
    int chain = blockIdx.x * 256 + threadIdx.x;   // 65536 chains
    float h = 0.f;
    for (int c = 0; c < NCH; c++) {
        hin[(size_t)c * 65536 + chain] = h;
        float2 v = hA[(size_t)c * 65536 + chain];
        h = fmaf(v.y, h, v.x);
    }
}

__global__ __launch_bounds__(256)
void scan_phaseC(const float* __restrict__ delta, const float* __restrict__ u,
                 const float* __restrict__ u_res, const float* __restrict__ x_dbl,
                 const float* __restrict__ A_log, const float* __restrict__ Dw,
                 const float* __restrict__ hin, __hip_bfloat16* __restrict__ y)
{
    __shared__ float sB[64][16], sC[64][16];
    const int tid = threadIdx.x;
    const int b = blockIdx.z, cg = blockIdx.y;
    const int lane = tid & 63, w = tid >> 6;
    const int d = blockIdx.x * 64 + lane;
    const int c = cg * 4 + w;
    const int tok0 = b * SEQ + cg * 64;

    #pragma unroll
    for (int i = 0; i < 4; i++) {
        int e = tid + 256 * i;
        int tt = e >> 4, n = e & 15;
        sB[tt][n] = x_dbl[(size_t)(tok0 + tt) * 96 + DTRANK + n];
        sC[tt][n] = x_dbl[(size_t)(tok0 + tt) * 96 + DTRANK + DSTATE + n];
    }
    __syncthreads();

    float An[16];
    #pragma unroll
    for (int n = 0; n < 16; n++) An[n] = -__expf(A_log[d * 16 + n]);

    float h[16];
    size_t hbase = (size_t)c * 65536 + ((size_t)(b * DINNER + d)) * 16;
    #pragma unroll
    for (int n = 0; n < 16; n++) h[n] = hin[hbase + n];
    const float Dd = Dw[d];
    const int tw0 = w * CHT;

    for (int t = 0; t < CHT; t++) {
        int tok = tok0 + tw0 + t;
        float dv = delta[(size_t)tok * DINNER + d];
        float uv = u[(size_t)tok * DINNER + d];
        float rv = u_res[(size_t)tok * (2 * DINNER) + DINNER + d];
        float duv = dv * uv;
        float s0 = 0.f, s1 = 0.f, s2 = 0.f, s3 = 0.f;
        #pragma unroll
        for (int g = 0; g < 4; g++) {
            #pragma unroll
            for (int q = 0; q < 4; q++) {
                int n = g * 4 + q;
                float dA = __expf(dv * An[n]);
                h[n] = fmaf(dA, h[n], sB[tw0 + t][n] * duv);
                if (g == 0) s0 = fmaf(h[n], sC[tw0 + t][n], s0);
                else if (g == 1) s1 = fmaf(h[n], sC[tw0 + t][n], s1);
                else if (g == 2) s2 = fmaf(h[n], sC[tw0 + t][n], s2);
                else s3 = fmaf(h[n], sC[tw0 + t][n], s3);
            }
        }
        float s = (s0 + s1) + (s2 + s3);
        float sig = 1.f / (1.f + __expf(-rv));
        y[(size_t)tok * DINNER + d] = __float2bfloat16((s + uv * Dd) * (rv * sig));
    }
}

// ---------------------------------------------------------------------------
__device__ __forceinline__ float block_reduce(float v, float* sh, bool is_max)
{
    int tid = threadIdx.x;
    sh[tid] = v;
    __syncthreads();
    #pragma unroll
    for (int s = 128; s > 0; s >>= 1) {
        if (tid < s) sh[tid] = is_max ? fmaxf(sh[tid], sh[tid + s]) : (sh[tid] + sh[tid + s]);
        __syncthreads();
    }
    float r = sh[0];
    __syncthreads();
    return r;
}

__global__ __launch_bounds__(256)
void rmsnorm_quant_kernel(const float* __restrict__ x, const float* __restrict__ parts,
                          size_t pstride, const float* __restrict__ w,
                          float* __restrict__ h_out,
                          __hip_bfloat16* __restrict__ q_out, float* __restrict__ dq_out)
{
    __shared__ float sh[256];
    const int row = blockIdx.x;
    const int tid = threadIdx.x;
    float v[4]; float ss = 0.f;
    #pragma unroll
    for (int i = 0; i < 4; i++) {
        size_t idx = (size_t)row * DMODEL + tid + 256 * i;
        float s = x[idx] + parts[idx] + parts[idx + pstride]
                + parts[idx + 2 * pstride] + parts[idx + 3 * pstride];
        v[i] = s; ss = fmaf(s, s, ss);
    }
    float tot = block_reduce(ss, sh, false);
    float scale = rsqrtf(tot * (1.f / DMODEL) + 1e-6f);
    float hv[4]; float amax = 0.f;
    #pragma unroll
    for (int i = 0; i < 4; i++) {
        int cidx = tid + 256 * i;
        hv[i] = v[i] * scale * w[cidx];
        amax = fmaxf(amax, fabsf(hv[i]));
    }
    float xm = fmaxf(block_reduce(amax, sh, true), 1e-5f);
    float qs = 127.f / xm;
    #pragma unroll
    for (int i = 0; i < 4; i++) {
        int cidx = tid + 256 * i;
        float q = rintf(hv[i] * qs);
        q = fmaxf(-128.f, fminf(127.f, q));
        h_out[(size_t)row * DMODEL + cidx] = hv[i];
        q_out[(size_t)row * DMODEL + cidx] = __float2bfloat16(q);
    }
    if (tid == 0) dq_out[row] = xm / 127.f;
}

__global__ __launch_bounds__(256)
void quant_rows_kernel(const float* __restrict__ in, __hip_bfloat16* __restrict__ out,
                       float* __restrict__ dq_out)
{
    __shared__ float sh[256];
    const int row = blockIdx.x;
    const int tid = threadIdx.x;
    float v[16]; float amax = 0.f;
    #pragma unroll
    for (int i = 0; i < 16; i++) {
        int cidx = tid + 256 * i;
        v[i] = in[(size_t)row * DFF + cidx];
        amax = fmaxf(amax, fabsf(v[i]));
    }
    float xm = fmaxf(block_reduce(amax, sh, true), 1e-5f);
    float qs = 127.f / xm;
    #pragma unroll
    for (int i = 0; i < 16; i++) {
        int cidx = tid + 256 * i;
        float q = rintf(v[i] * qs);
        q = fmaxf(-128.f, fminf(127.f, q));
        out[(size_t)row * DFF + cidx] = __float2bfloat16(q);
    }
    if (tid == 0) dq_out[row] = xm / 127.f;
}

__global__ __launch_bounds__(256)
void rmsnorm_out_kernel(const float* __restrict__ h1, const float* __restrict__ parts,
                        size_t pstride, const float* __restrict__ dq2,
                        const float* __restrict__ wsum, float winv,
                        const float* __restrict__ w, float* __restrict__ out)
{
    __shared__ float sh[256];
    const int row = blockIdx.x;
    const int tid = threadIdx.x;
    float rs = dq2[row] * fmaxf(wsum[0] * winv, 1e-5f);
    float v[4]; float ss = 0.f;
    #pragma unroll
    for (int i = 0; i < 4; i++) {
        size_t idx = (size_t)row * DMODEL + tid + 256 * i;
        float f = (parts[idx] + parts[idx + pstride]
                 + parts[idx + 2 * pstride] + parts[idx + 3 * pstride]) * rs;
        float s = h1[idx] + f;
        v[i] = s; ss = fmaf(s, s, ss);
    }
    float tot = block_reduce(ss, sh, false);
    float scale = rsqrtf(tot * (1.f / DMODEL) + 1e-6f);
    #pragma unroll
    for (int i = 0; i < 4; i++) {
        int cidx = tid + 256 * i;
        out[(size_t)row * DMODEL + cidx] = v[i] * scale * w[cidx];
    }
}

__global__ __launch_bounds__(256)
void wabs_kernel(const float* __restrict__ w, int n, float* __restrict__ out)
{
    float s = 0.f;
    for (int i = blockIdx.x * blockDim.x + threadIdx.x; i < n; i += gridDim.x * blockDim.x)
        s += fabsf(w[i]);
    #pragma unroll
    for (int off = 32; off >= 1; off >>= 1) s += __shfl_down(s, off, 64);
    __shared__ float sh[4];
    int lane = threadIdx.x & 63, wv = threadIdx.x >> 6;
    if (lane == 0) sh[wv] = s;
    __syncthreads();
    if (threadIdx.x == 0) atomicAdd(out, sh[0] + sh[1] + sh[2] + sh[3]);
}

// ---------------------------------------------------------------------------
// Workspace (float offsets; M1 = 1M floats):
//  A [0,8M)    u_res (G1..phaseC) -> op_parts (G6..rmsq) -> gu (gateup..qrows)
//              -> dn_parts (down..rmsout)
//  B [8M,12M)  u_f (conv..phaseC)
//  C [12M,14M) u_b bf16 (conv..G3) -> y_b bf16 (phaseC..G6)
//  D [14M,18M) delta (G4..phaseC) -> wq_gate+wq_up (tern..gateup) -> guq (..down)
//  E+F [18M,22M) w_in_b bf16 (f2b..G1), x_b bf16 [21M,22M) (f2b..G1)
//              -> hin (combine..phaseC) -> wq_down [18M,20M) + h1 [20M,21M)... 
//              NOTE: h1 lives at [20.5M? no] -- h1 at [22M..]? see below
//  G [22M,23M) w_out_b bf16 (..G6) -> xq_b bf16 (rmsq..gateup)
//  J [23M,23.7M) x_dbl, x_dbl_b, w_x_b, w_dt_b, dq1, dq2, wsums, h1
//  X [24M,32M) x_parts (G3..reduce) -> hA float2 (phaseA..combine)
//  h1 needs 2M: place at [30M,32M) after hA's combine use? hA alive until
//  combine only; rmsq (h1 write) is after phaseC > combine. OK: h1=[30M,32M).
// ---------------------------------------------------------------------------
extern "C" void kernel_launch(void* const* d_in, const int* in_sizes, int n_in,
                              void* d_out, int out_size, void* d_ws, size_t ws_size,
                              hipStream_t stream)
{
    const float* x         = (const float*)d_in[0];
    const float* in_proj_w = (const float*)d_in[1];
    const float* conv_w    = (const float*)d_in[2];
    const float* conv_b    = (const float*)d_in[3];
    const float* x_proj_w  = (const float*)d_in[4];
    const float* dt_proj_w = (const float*)d_in[5];
    const float* dt_proj_b = (const float*)d_in[6];
    const float* A_log     = (const float*)d_in[7];
    const float* Dw        = (const float*)d_in[8];
    const float* out_proj_w= (const float*)d_in[9];
    const float* norm1_w   = (const float*)d_in[10];
    const float* gate_w    = (const float*)d_in[11];
    const float* up_w      = (const float*)d_in[12];
    const float* down_w    = (const float*)d_in[13];
    const float* norm2_w   = (const float*)d_in[14];
    float* out = (float*)d_out;

    typedef __hip_bfloat16 bf16;
    float* ws = (float*)d_ws;
    const size_t M1 = 1024 * 1024;

    float* u_res    = ws + 0;                        // A
    float* op_parts = ws + 0;
    float* gu       = ws + 0;
    float* dn_parts = ws + 0;
    float* u_f      = ws + 8 * M1;                   // B
    bf16*  u_b      = (bf16*)(ws + 12 * M1);         // C
    bf16*  y_b      = (bf16*)(ws + 12 * M1);
    float* delta    = ws + 14 * M1;                  // D
    bf16*  wq_gate  = (bf16*)(ws + 14 * M1);
    bf16*  wq_up    = (bf16*)(ws + 16 * M1);
    bf16*  guq      = (bf16*)(ws + 14 * M1);
    bf16*  w_in_b   = (bf16*)(ws + 18 * M1);         // E+F
    float* hin      = ws + 18 * M1;                  // 4M (combine..phaseC)
    bf16*  wq_down  = (bf16*)(ws + 18 * M1);         // 2M fl (after phaseC)
    bf16*  x_b      = (bf16*)(ws + 21 * M1);
    bf16*  w_out_b  = (bf16*)(ws + 22 * M1);         // G
    bf16*  xq_b     = (bf16*)(ws + 22 * M1);
    float* x_dbl    = ws + 23 * M1;                  // J
    bf16*  x_dbl_b  = (bf16*)(ws + 23 * M1 + 262144);
    bf16*  w_x_b    = (bf16*)(ws + 23 * M1 + 393216);
    bf16*  w_dt_b   = (bf16*)(ws + 23 * M1 + 524288);
    float* dq1      = ws + 23 * M1 + 655360;
    float* dq2      = ws + 23 * M1 + 659456;
    float* wsums    = ws + 23 * M1 + 663552;
    float* x_parts  = ws + 24 * M1;                  // X
    float2* hA      = (float2*)(ws + 24 * M1);       // 8M fl (phaseA..combine)
    float* h1       = ws + 30 * M1;                  // 2M (rmsq..end; hA dead)

    dim3 blk(256);
    const float winv = 1.f / (float)(DFF * DMODEL);

    hipMemsetAsync(wsums, 0, 16, stream);
    wabs_kernel<<<512, blk, 0, stream>>>(gate_w, DFF * DMODEL, wsums + 0);
    wabs_kernel<<<512, blk, 0, stream>>>(up_w,   DFF * DMODEL, wsums + 1);
    wabs_kernel<<<512, blk, 0, stream>>>(down_w, DMODEL * DFF, wsums + 2);

    f2b_kernel<<<1024, blk, 0, stream>>>(x, x_b, NTOK * DMODEL);
    f2b_kernel<<<1024, blk, 0, stream>>>(in_proj_w, w_in_b, 2 * DINNER * DMODEL);
    f2b_kernel<<<256, blk, 0, stream>>>(x_proj_w, w_x_b, 96 * DINNER);
    f2b_kernel<<<256, blk, 0, stream>>>(dt_proj_w, w_dt_b, DINNER * DTRANK);
    f2b_kernel<<<1024, blk, 0, stream>>>(out_proj_w, w_out_b, DMODEL * DINNER);

    // 1. u_res = x @ in_proj^T  [2048,4096]
    mfma_gemm<0, false><<<dim3(32, 16), blk, 0, stream>>>(
        x_b, DMODEL, w_in_b, DMODEL, u_res, 2 * DINNER, nullptr,
        NTOK, 2 * DINNER, DMODEL, nullptr, 0);

    // 2. conv + silu
    conv_silu_kernel<<<(NTOK * DINNER) / 256, blk, 0, stream>>>(u_res, conv_w, conv_b, u_f, u_b);

    // 3. x_dbl = u @ x_proj^T  [2048,96], split-K=8 -> reduce
    mfma_gemm<0, false><<<dim3(1, 16, 8), blk, 0, stream>>>(
        u_b, DINNER, w_x_b, DINNER, x_parts, 96, nullptr,
        NTOK, 96, DINNER, nullptr, NTOK * 96);
    xproj_reduce<<<(NTOK * 96 + 255) / 256, blk, 0, stream>>>(x_parts, x_dbl, x_dbl_b);

    // 4. delta = softplus(dt @ dt_proj^T + b)  [2048,2048]
    mfma_gemm<1, false><<<dim3(16, 16), blk, 0, stream>>>(
        x_dbl_b, 96, w_dt_b, DTRANK, delta, DINNER, nullptr,
        NTOK, DINNER, DTRANK, dt_proj_b, 0);

    // 5. chunked scan (thread-per-d, 16 states in registers)
    scan_phaseA<<<dim3(32, 16, 2), blk, 0, stream>>>(delta, u_f, x_dbl, A_log, hA);
    scan_combine<<<256, blk, 0, stream>>>(hA, hin);
    scan_phaseC<<<dim3(32, 16, 2), blk, 0, stream>>>(delta, u_f, u_res, x_dbl, A_log, Dw, hin, y_b);

    // ternarize (delta dead after phaseC; hin dead after phaseC)
    ternarize_kernel<<<1024, blk, 0, stream>>>(gate_w, wq_gate, DFF * DMODEL, wsums + 0, winv);
    ternarize_kernel<<<1024, blk, 0, stream>>>(up_w,   wq_up,   DFF * DMODEL, wsums + 1, winv);
    ternarize_kernel<<<1024, blk, 0, stream>>>(down_w, wq_down, DMODEL * DFF, wsums + 2, winv);

    // 6. out_proj split-K=4 -> op_parts (region A; u_res dead after phaseC)
    mfma_gemm<0, false><<<dim3(8, 16, 4), blk, 0, stream>>>(
        y_b, DINNER, w_out_b, DINNER, op_parts, DMODEL, nullptr,
        NTOK, DMODEL, DINNER, nullptr, 2 * M1);

    // 7. h1 = rmsnorm(x + sum(op_parts)); xq + dq1
    rmsnorm_quant_kernel<<<NTOK, blk, 0, stream>>>(x, op_parts, 2 * M1, norm1_w, h1, xq_b, dq1);

    // 8. gu = sigmoid(gate)*up fused  [2048,4096]
    mfma_gateup<<<dim3(32, 16), blk, 0, stream>>>(
        xq_b, wq_gate, wq_up, gu, dq1, wsums + 0, wsums + 1, winv);

    // 9. guq + dq2
    quant_rows_kernel<<<NTOK, blk, 0, stream>>>(gu, guq, dq2);

    // 10. down split-K=4 -> dn_parts
    mfma_gemm<0, false><<<dim3(8, 16, 4), blk, 0, stream>>>(
        guq, DFF, wq_down, DFF, dn_parts, DMODEL, nullptr,
        NTOK, DMODEL, DFF, nullptr, 2 * M1);

    // 11. out = rmsnorm(h1 + sum(dn_parts)*dq2*ws)
    rmsnorm_out_kernel<<<NTOK, blk, 0, stream>>>(h1, dn_parts, 2 * M1, dq2,
                                                 wsums + 2, winv, norm2_w, out);
}